// Round 4
// baseline (3049.437 us; speedup 1.0000x reference)
//
#include <hip/hip_runtime.h>

#define B_ 16
#define N_ 4096
#define M_ 1024
#define S_ 32
#define IN_ 64
#define C0IN 67
#define C0 64
#define C1 64
#define C2 128
#define NTOT (B_*M_*S_)
#define R2 0.04f
#define CAP 1024
#define NBUCK 16

#define FPS_T 512
#define FPS_PTS (N_ / FPS_T)   // 8 points per lane

// DPP wave-64 reductions at VALU speed (no DS ops).
#define DPP_F32_MAX(v, ctrl) \
    v = fmaxf(v, __int_as_float(__builtin_amdgcn_update_dpp( \
            __float_as_int(v), __float_as_int(v), ctrl, 0xF, 0xF, false)))
#define DPP_S32_MIN(v, ctrl) \
    { int _o = __builtin_amdgcn_update_dpp(v, v, ctrl, 0xF, 0xF, false); \
      v = _o < v ? _o : v; }

// ---------------- FPS ----------------
// One 512-thread block (8 waves) per batch. 8 points/lane in VGPRs, loaded
// DIRECTLY FROM GLOBAL (no LDS provenance -> compiler cannot remat as LDS
// reads; round-1 showed VGPR=68 i.e. coords were re-read from LDS).
// LDS keeps a float4 copy ONLY for the uniform center-broadcast read.
// Per iter: dist update -> DPP value-max + idx-min reduces -> double-buffered
// 8-slot cross-wave reduce, ONE barrier. Tie-break (dist desc, idx asc).
__global__ __launch_bounds__(FPS_T, 1) void fps_kernel(const float* __restrict__ xyz,
                                                       int* __restrict__ fps_idx,
                                                       float* __restrict__ out_xyz) {
#pragma clang fp contract(off)
    __shared__ float4 pxyz[N_];
    __shared__ int    sel[M_];
    __shared__ float  rv[2][8];
    __shared__ int    ri[2][8];
    int b = blockIdx.x, t = threadIdx.x;
    const float* xb = xyz + (size_t)b * N_ * 3;
    float lx[FPS_PTS], ly[FPS_PTS], lz[FPS_PTS], dl[FPS_PTS];
#pragma unroll
    for (int j = 0; j < FPS_PTS; j++) {
        int i = (j << 9) + t;
        float x = xb[3*i], y = xb[3*i+1], z = xb[3*i+2];
        lx[j] = x; ly[j] = y; lz[j] = z;
        dl[j] = __builtin_inff();
        pxyz[i] = make_float4(x, y, z, 0.f);
    }
    __syncthreads();
    int wid = t >> 6, lane = t & 63;
    int cur = 0;
    float4 cc = pxyz[0];
    for (int k = 0; k < M_; k++) {
        float cx = cc.x, cy = cc.y, cz = cc.z;
        if (t == 0) sel[k] = cur;
        // re-pin coords every iteration: forbids LDS/global remat
#pragma unroll
        for (int j = 0; j < FPS_PTS; j++)
            asm volatile("" : "+v"(lx[j]), "+v"(ly[j]), "+v"(lz[j]));
        float bv = -1.0f; int bi = 0x7fffffff;
#pragma unroll
        for (int j = 0; j < FPS_PTS; j++) {
            float dx = lx[j] - cx, dy = ly[j] - cy, dz = lz[j] - cz;
            float t0 = dx*dx, t1 = dy*dy, t2 = dz*dz;
            float d = (t0 + t1) + t2;
            float od = dl[j];
            float nd = d < od ? d : od;
            dl[j] = nd;
            if (nd > bv) { bv = nd; bi = (j << 9) + t; }  // strict > keeps smallest idx per lane
        }
        // wave argmax: value max -> lane63 -> broadcast; then idx min among ties
        float m = bv;
        DPP_F32_MAX(m, 0x111); DPP_F32_MAX(m, 0x112); DPP_F32_MAX(m, 0x114);
        DPP_F32_MAX(m, 0x118); DPP_F32_MAX(m, 0x142); DPP_F32_MAX(m, 0x143);
        float wmax = __int_as_float(__builtin_amdgcn_readlane(__float_as_int(m), 63));
        int cand = (bv == wmax) ? bi : 0x7fffffff;
        DPP_S32_MIN(cand, 0x111); DPP_S32_MIN(cand, 0x112); DPP_S32_MIN(cand, 0x114);
        DPP_S32_MIN(cand, 0x118); DPP_S32_MIN(cand, 0x142); DPP_S32_MIN(cand, 0x143);
        int widx = __builtin_amdgcn_readlane(cand, 63);
        // cross-wave reduce (8 slots), double-buffered, ONE barrier
        int p = k & 1;
        if (lane == 0) { rv[p][wid] = wmax; ri[p][wid] = widx; }
        __syncthreads();
        float gv = rv[p][0]; int gi = ri[p][0];
#pragma unroll
        for (int j = 1; j < 8; j++) {
            float ov = rv[p][j]; int oi = ri[p][j];
            if (ov > gv || (ov == gv && oi < gi)) { gv = ov; gi = oi; }
        }
        cur = gi;
        cc = pxyz[cur];   // single uniform ds_read_b128
    }
    __syncthreads();
    for (int i = t; i < M_; i += FPS_T) {
        int ix = sel[i];
        float4 q = pxyz[ix];
        fps_idx[b*M_ + i] = ix;
        out_xyz[(b*M_ + i)*3 + 0] = q.x;
        out_xyz[(b*M_ + i)*3 + 1] = q.y;
        out_xyz[(b*M_ + i)*3 + 2] = q.z;
    }
}

// ---------------- Ball query ---------------- (unchanged, proven)
__global__ __launch_bounds__(256) void ballq_kernel(const float* __restrict__ xyz,
                                                    const int* __restrict__ fps_idx,
                                                    int* __restrict__ ball_idx) {
#pragma clang fp contract(off)
    __shared__ float cd[CAP];
    __shared__ int   ci[CAP];
    __shared__ int   cnt;
    __shared__ float rv[4];
    __shared__ int   ri[4];
    __shared__ int   slots[33];
    int blk = blockIdx.x;
    int b = blk >> 10, m = blk & (M_ - 1);
    int t = threadIdx.x;
    if (t == 0) cnt = 0;
    __syncthreads();
    const float* xb = xyz + (size_t)b * N_ * 3;
    int cidx = fps_idx[b*M_ + m];
    float cx = xb[cidx*3+0], cy = xb[cidx*3+1], cz = xb[cidx*3+2];
    float bv = 3.4e38f; int bi = 0x7fffffff;
    for (int i = t; i < N_; i += 256) {
        float dx = xb[i*3+0] - cx, dy = xb[i*3+1] - cy, dz = xb[i*3+2] - cz;
        float t0 = dx*dx, t1 = dy*dy, t2 = dz*dz;
        float d = (t0 + t1) + t2;
        if (d < bv || (d == bv && i < bi)) { bv = d; bi = i; }
        if (d <= R2) {
            int p = atomicAdd(&cnt, 1);
            if (p < CAP) { cd[p] = d; ci[p] = i; }
        }
    }
    for (int off = 32; off >= 1; off >>= 1) {
        float ov = __shfl_xor(bv, off, 64);
        int   oi = __shfl_xor(bi, off, 64);
        if (ov < bv || (ov == bv && oi < bi)) { bv = ov; bi = oi; }
    }
    int w = t >> 6;
    if ((t & 63) == 0) { rv[w] = bv; ri[w] = bi; }
    __syncthreads();
    int n = cnt < CAP ? cnt : CAP;
    for (int j = t; j < n; j += 256) {
        float dj = cd[j]; int ij = ci[j];
        int rank = 0;
        for (int k = 0; k < n; k++) {
            float dk = cd[k]; int ik = ci[k];
            rank += (dk < dj) || (dk == dj && ik < ij);
        }
        if (rank < S_) slots[rank] = ij;
    }
    if (t == 0) {
        float v = rv[0]; int ix = ri[0];
        for (int j = 1; j < 4; j++)
            if (rv[j] < v || (rv[j] == v && ri[j] < ix)) { v = rv[j]; ix = ri[j]; }
        slots[32] = ix;
    }
    __syncthreads();
    if (t < S_) {
        int nearest = (n > 0) ? slots[0] : slots[32];
        int ix = (t < n) ? slots[t] : nearest;
        ball_idx[(size_t)(b*M_ + m)*S_ + t] = ix;
    }
}

// uniform-broadcast float4 dot with register-resident weight row; order = c asc.
template<int LEN>
__device__ __forceinline__ float dotu(const float* xr, const float (&wr)[LEN], float acc) {
#pragma unroll
    for (int c = 0; c + 4 <= LEN; c += 4) {
        float4 v = *(const float4*)(xr + c);
        acc += v.x * wr[c];
        acc += v.y * wr[c+1];
        acc += v.z * wr[c+2];
        acc += v.w * wr[c+3];
    }
#pragma unroll
    for (int c = (LEN & ~3); c < LEN; c++) acc += xr[c] * wr[c];
    return acc;
}

// ---------------- Staged MLP pipeline ----------------
// Compute each layer ONCE; pre-BN activations staged to global ws.
// stats: NBUCK buckets x 512 floats (bucket = blk & (NBUCK-1)).
// layout within bucket: [sum0 64 | sq0 64 | sum1 64 | sq1 64 | sum2 128 | sq2 128]

__global__ __launch_bounds__(256) void mlpA_kernel(
    const float* __restrict__ xyz, const float* __restrict__ feat,
    const int* __restrict__ fps_idx, const int* __restrict__ ball_idx,
    const float* __restrict__ w0, const float* __restrict__ b0,
    float* __restrict__ z0, float* __restrict__ stats) {
    __shared__ float xs[S_][68];
    __shared__ float red[256], red2[256];
    __shared__ int idxs[S_];
    int blk = blockIdx.x, b = blk >> 10, m = blk & (M_ - 1), t = threadIdx.x;
    const float* xb = xyz + (size_t)b * N_ * 3;
    int cidx = fps_idx[b*M_ + m];
    float cx = xb[cidx*3+0], cy = xb[cidx*3+1], cz = xb[cidx*3+2];
    if (t < S_) idxs[t] = ball_idx[(size_t)blk * S_ + t];
    __syncthreads();
    for (int i = t; i < S_*C0IN; i += 256) {
        int s = i / C0IN, c = i - s * C0IN;
        int p = idxs[s];
        float v;
        if (c == 0)      v = xb[p*3+0] - cx;
        else if (c == 1) v = xb[p*3+1] - cy;
        else if (c == 2) v = xb[p*3+2] - cz;
        else             v = feat[((size_t)b*N_ + p)*IN_ + (c - 3)];
        xs[s][c] = v;
    }
    __syncthreads();
    int d = t & 63;
    float wr[C0IN];
    {
        const float* w = w0 + d * C0IN;
#pragma unroll
        for (int c = 0; c < C0IN; c++) wr[c] = w[c];
    }
    float bias = b0[d];
    float lsum = 0.f, lsq = 0.f;
#pragma unroll
    for (int q = 0; q < 8; q++) {
        int s = (t >> 6) + q * 4;
        float a = dotu<C0IN>(&xs[s][0], wr, bias);
        z0[(size_t)blk * 2048 + s*64 + d] = a;   // addr = blk*2048 + t + 256q (coalesced)
        lsum += a; lsq += a * a;
    }
    red[t] = lsum; red2[t] = lsq;
    __syncthreads();
    if (t < 64) {
        float* sb = stats + (size_t)(blk & (NBUCK-1)) * 512;
        atomicAdd(&sb[t],      red[t]  + red[t+64]  + red[t+128]  + red[t+192]);
        atomicAdd(&sb[64 + t], red2[t] + red2[t+64] + red2[t+128] + red2[t+192]);
    }
}

__global__ __launch_bounds__(256) void mlpB_kernel(
    const float* __restrict__ z0, const float* __restrict__ w1, const float* __restrict__ b1,
    const float* __restrict__ coef, float* __restrict__ z1, float* __restrict__ stats) {
    __shared__ float xs[S_][C0];
    __shared__ float red[256], red2[256];
    int blk = blockIdx.x, t = threadIdx.x;
    int d = t & 63;
    float a0 = coef[d], c0 = coef[64 + d];
    const float* zt = z0 + (size_t)blk * 2048;
#pragma unroll
    for (int j = 0; j < 8; j++) {
        int i = t + j * 256;          // channel = t&63, s = (t>>6)+4j; coalesced
        float v = zt[i] * a0 + c0;
        xs[i >> 6][d] = v > 0.f ? v : 0.f;
    }
    float wr[C0];
    {
        const float* w = w1 + d * C0;
#pragma unroll
        for (int c = 0; c < C0; c++) wr[c] = w[c];
    }
    float bias = b1[d];
    __syncthreads();
    float lsum = 0.f, lsq = 0.f;
#pragma unroll
    for (int q = 0; q < 8; q++) {
        int s = (t >> 6) + q * 4;
        float a = dotu<C0>(&xs[s][0], wr, bias);
        z1[(size_t)blk * 2048 + s*64 + d] = a;
        lsum += a; lsq += a * a;
    }
    red[t] = lsum; red2[t] = lsq;
    __syncthreads();
    if (t < 64) {
        float* sb = stats + (size_t)(blk & (NBUCK-1)) * 512;
        atomicAdd(&sb[128 + t], red[t]  + red[t+64]  + red[t+128]  + red[t+192]);
        atomicAdd(&sb[192 + t], red2[t] + red2[t+64] + red2[t+128] + red2[t+192]);
    }
}

__global__ __launch_bounds__(256) void mlpC_kernel(
    const float* __restrict__ z1, const float* __restrict__ w2, const float* __restrict__ b2,
    const float* __restrict__ coef, float* __restrict__ z2, float* __restrict__ stats) {
    __shared__ float xs[S_][C1];
    __shared__ float red[256], red2[256];
    int blk = blockIdx.x, t = threadIdx.x;
    {
        int dn = t & 63;
        float a1 = coef[128 + dn], c1 = coef[192 + dn];
        const float* zt = z1 + (size_t)blk * 2048;
#pragma unroll
        for (int j = 0; j < 8; j++) {
            int i = t + j * 256;
            float v = zt[i] * a1 + c1;
            xs[i >> 6][dn] = v > 0.f ? v : 0.f;
        }
    }
    int d = t & 127;
    float wr[C1];
    {
        const float* w = w2 + d * C1;
#pragma unroll
        for (int c = 0; c < C1; c++) wr[c] = w[c];
    }
    float bias = b2[d];
    __syncthreads();
    float lsum = 0.f, lsq = 0.f;
#pragma unroll
    for (int q = 0; q < 16; q++) {
        int s = (t >> 7) + q * 2;
        float a = dotu<C1>(&xs[s][0], wr, bias);
        z2[(size_t)blk * 4096 + s*128 + d] = a;  // addr = blk*4096 + t + 256q (coalesced)
        lsum += a; lsq += a * a;
    }
    red[t] = lsum; red2[t] = lsq;
    __syncthreads();
    if (t < 128) {
        float* sb = stats + (size_t)(blk & (NBUCK-1)) * 512;
        atomicAdd(&sb[256 + t], red[t]  + red[t+128]);
        atomicAdd(&sb[384 + t], red2[t] + red2[t+128]);
    }
}

__global__ __launch_bounds__(256) void mlpD_kernel(
    const float* __restrict__ z2, const float* __restrict__ coef,
    float* __restrict__ out_feat) {
    __shared__ float red[256];
    int blk = blockIdx.x, t = threadIdx.x;
    int d = t & 127;
    float a2 = coef[256 + d], c2 = coef[384 + d];
    const float* zt = z2 + (size_t)blk * 4096;
    float lmax = -3.4e38f;
#pragma unroll
    for (int j = 0; j < 16; j++) {
        float v = zt[t + 256*j] * a2 + c2;   // channel = t&127 for all j
        v = v > 0.f ? v : 0.f;
        lmax = v > lmax ? v : lmax;
    }
    red[t] = lmax;
    __syncthreads();
    if (t < 128) {
        float v = red[t] > red[t+128] ? red[t] : red[t+128];
        out_feat[(size_t)blk * C2 + t] = v;
    }
}

// ---------------- Fallback 4-pass MLP (used when ws too small) ----------------
template<int MODE>
__global__ __launch_bounds__(256) void mlp_kernel(
    const float* __restrict__ xyz, const float* __restrict__ feat,
    const int* __restrict__ fps_idx, const int* __restrict__ ball_idx,
    const float* __restrict__ w0, const float* __restrict__ b0,
    const float* __restrict__ w1, const float* __restrict__ b1,
    const float* __restrict__ w2, const float* __restrict__ b2,
    const float* __restrict__ coef, float* __restrict__ stats,
    float* __restrict__ out_feat) {
    __shared__ float xs[S_*C0IN];
    __shared__ float y0s[S_*C0];
    __shared__ float y1s[S_*C1];
    __shared__ float red[256];
    __shared__ float red2[256];
    __shared__ int idxs[S_];
    int blk = blockIdx.x;
    int b = blk >> 10, m = blk & (M_ - 1);
    int t = threadIdx.x;
    const float* xb = xyz + (size_t)b * N_ * 3;
    int cidx = fps_idx[b*M_ + m];
    float cx = xb[cidx*3+0], cy = xb[cidx*3+1], cz = xb[cidx*3+2];
    if (t < S_) idxs[t] = ball_idx[(size_t)(b*M_ + m)*S_ + t];
    __syncthreads();
    for (int i = t; i < S_*C0IN; i += 256) {
        int s = i / C0IN, c = i - s * C0IN;
        int p = idxs[s];
        float v;
        if (c == 0)      v = xb[p*3+0] - cx;
        else if (c == 1) v = xb[p*3+1] - cy;
        else if (c == 2) v = xb[p*3+2] - cz;
        else             v = feat[((size_t)b*N_ + p)*IN_ + (c - 3)];
        xs[i] = v;
    }
    __syncthreads();
    {
        float lsum = 0.f, lsq = 0.f;
        int d = t & 63;
        for (int o = t; o < S_*C0; o += 256) {
            int s = o >> 6;
            float acc = b0[d];
            const float* wr = w0 + d * C0IN;
            const float* xr = xs + s * C0IN;
            for (int c = 0; c < C0IN; c++) acc += xr[c] * wr[c];
            if (MODE == 0) { lsum += acc; lsq += acc * acc; }
            else {
                float v = acc * coef[d] + coef[64 + d];
                y0s[s*C0 + d] = v > 0.f ? v : 0.f;
            }
        }
        if (MODE == 0) {
            red[t] = lsum; red2[t] = lsq;
            __syncthreads();
            if (t < 64) {
                atomicAdd(&stats[t],      red[t]  + red[t+64]  + red[t+128]  + red[t+192]);
                atomicAdd(&stats[64 + t], red2[t] + red2[t+64] + red2[t+128] + red2[t+192]);
            }
            return;
        }
    }
    __syncthreads();
    {
        float lsum = 0.f, lsq = 0.f;
        int d = t & 63;
        for (int o = t; o < S_*C1; o += 256) {
            int s = o >> 6;
            float acc = b1[d];
            const float* wr = w1 + d * C0;
            const float* yr = y0s + s * C0;
            for (int c = 0; c < C0; c++) acc += yr[c] * wr[c];
            if (MODE == 1) { lsum += acc; lsq += acc * acc; }
            else {
                float v = acc * coef[128 + d] + coef[192 + d];
                y1s[s*C1 + d] = v > 0.f ? v : 0.f;
            }
        }
        if (MODE == 1) {
            red[t] = lsum; red2[t] = lsq;
            __syncthreads();
            if (t < 64) {
                atomicAdd(&stats[128 + t], red[t]  + red[t+64]  + red[t+128]  + red[t+192]);
                atomicAdd(&stats[192 + t], red2[t] + red2[t+64] + red2[t+128] + red2[t+192]);
            }
            return;
        }
    }
    __syncthreads();
    {
        int d = t & 127;
        float lsum = 0.f, lsq = 0.f, lmax = -3.4e38f;
        for (int o = t; o < S_*C2; o += 256) {
            int s = o >> 7;
            float acc = b2[d];
            const float* wr = w2 + d * C1;
            const float* yr = y1s + s * C1;
            for (int c = 0; c < C1; c++) acc += yr[c] * wr[c];
            if (MODE == 2) { lsum += acc; lsq += acc * acc; }
            else {
                float v = acc * coef[256 + d] + coef[384 + d];
                v = v > 0.f ? v : 0.f;
                lmax = v > lmax ? v : lmax;
            }
        }
        if (MODE == 2) {
            red[t] = lsum; red2[t] = lsq;
            __syncthreads();
            if (t < 128) {
                atomicAdd(&stats[256 + t], red[t]  + red[t+128]);
                atomicAdd(&stats[384 + t], red2[t] + red2[t+128]);
            }
            return;
        }
        red[t] = lmax;
        __syncthreads();
        if (t < 128) {
            float v = red[t] > red[t+128] ? red[t] : red[t+128];
            out_feat[(size_t)(b*M_ + m)*C2 + t] = v;
        }
    }
}

// mean/var -> affine coefs; sums NBUCK stat buckets. y_n = y*a + c
__global__ void finalize_kernel(const float* __restrict__ stats,
                                const float* __restrict__ gamma,
                                const float* __restrict__ beta,
                                float* __restrict__ coef, int C, int off) {
    int t = threadIdx.x;
    if (t < C) {
        float s = 0.f, s2 = 0.f;
        for (int j = 0; j < NBUCK; j++) {
            s  += stats[j*512 + off + t];
            s2 += stats[j*512 + off + C + t];
        }
        float inv_n = 1.0f / (float)NTOT;
        float mean = s * inv_n;
        float var = s2 * inv_n - mean * mean;
        float rstd = 1.0f / sqrtf(var + 1e-5f);
        float a = gamma[t] * rstd;
        coef[t] = a;
        coef[C + t] = beta[t] - mean * a;
    }
}

extern "C" void kernel_launch(void* const* d_in, const int* in_sizes, int n_in,
                              void* d_out, int out_size, void* d_ws, size_t ws_size,
                              hipStream_t stream) {
    const float* xyz  = (const float*)d_in[0];
    const float* feat = (const float*)d_in[1];
    const float* w0 = (const float*)d_in[2];  const float* b0 = (const float*)d_in[3];
    const float* g0 = (const float*)d_in[4];  const float* be0 = (const float*)d_in[5];
    const float* w1 = (const float*)d_in[6];  const float* b1 = (const float*)d_in[7];
    const float* g1 = (const float*)d_in[8];  const float* be1 = (const float*)d_in[9];
    const float* w2 = (const float*)d_in[10]; const float* b2 = (const float*)d_in[11];
    const float* g2 = (const float*)d_in[12]; const float* be2 = (const float*)d_in[13];
    float* out_xyz  = (float*)d_out;
    float* out_feat = out_xyz + B_*M_*3;

    int* fps_i  = (int*)d_ws;                                   // 64 KB
    int* ball_i = (int*)((char*)d_ws + 65536);                  // 2 MB
    size_t sbase = 65536 + 2097152;
    float* stats = (float*)((char*)d_ws + sbase);               // NBUCK*512*4 = 32 KB
    float* coef  = (float*)((char*)d_ws + sbase + NBUCK*512*4); // 2 KB
    size_t zoff = sbase + NBUCK*512*4 + 4096;                   // aligned
    float* z0 = (float*)((char*)d_ws + zoff);                   // NTOT*64  = 128 MB
    float* z1 = z0 + (size_t)NTOT * 64;                         // NTOT*64  = 128 MB
    float* z2 = z1 + (size_t)NTOT * 64;                         // NTOT*128 = 256 MB
    size_t need = zoff + (size_t)NTOT * 4 * (64 + 64 + 128);
    bool staged = ws_size >= need;

    hipMemsetAsync(stats, 0, NBUCK*512*sizeof(float), stream);
    fps_kernel<<<B_, FPS_T, 0, stream>>>(xyz, fps_i, out_xyz);
    ballq_kernel<<<B_*M_, 256, 0, stream>>>(xyz, fps_i, ball_i);

    if (staged) {
        mlpA_kernel<<<B_*M_, 256, 0, stream>>>(xyz, feat, fps_i, ball_i, w0, b0, z0, stats);
        finalize_kernel<<<1, 128, 0, stream>>>(stats, g0, be0, coef, 64, 0);
        mlpB_kernel<<<B_*M_, 256, 0, stream>>>(z0, w1, b1, coef, z1, stats);
        finalize_kernel<<<1, 128, 0, stream>>>(stats, g1, be1, coef + 128, 64, 128);
        mlpC_kernel<<<B_*M_, 256, 0, stream>>>(z1, w2, b2, coef, z2, stats);
        finalize_kernel<<<1, 128, 0, stream>>>(stats, g2, be2, coef + 256, 128, 256);
        mlpD_kernel<<<B_*M_, 256, 0, stream>>>(z2, coef, out_feat);
    } else {
        mlp_kernel<0><<<B_*M_, 256, 0, stream>>>(xyz, feat, fps_i, ball_i,
            w0, b0, w1, b1, w2, b2, coef, stats, out_feat);
        finalize_kernel<<<1, 128, 0, stream>>>(stats, g0, be0, coef, 64, 0);
        mlp_kernel<1><<<B_*M_, 256, 0, stream>>>(xyz, feat, fps_i, ball_i,
            w0, b0, w1, b1, w2, b2, coef, stats, out_feat);
        finalize_kernel<<<1, 128, 0, stream>>>(stats, g1, be1, coef + 128, 64, 128);
        mlp_kernel<2><<<B_*M_, 256, 0, stream>>>(xyz, feat, fps_i, ball_i,
            w0, b0, w1, b1, w2, b2, coef, stats, out_feat);
        finalize_kernel<<<1, 128, 0, stream>>>(stats, g2, be2, coef + 256, 128, 256);
        mlp_kernel<3><<<B_*M_, 256, 0, stream>>>(xyz, feat, fps_i, ball_i,
            w0, b0, w1, b1, w2, b2, coef, stats, out_feat);
    }
}

// Round 5
// 2661.819 us; speedup vs baseline: 1.1456x; 1.1456x over previous
//
#include <hip/hip_runtime.h>

#define B_ 16
#define N_ 4096
#define M_ 1024
#define S_ 32
#define IN_ 64
#define C0IN 67
#define C0 64
#define C1 64
#define C2 128
#define NTOT (B_*M_*S_)
#define R2 0.04f
#define CAP 1024
#define NBUCK 16

#define FPS_T 256
#define FPS_PTS 16   // 4096 / 256

// 64-bit DPP max (packed key). Two 32-bit DPP moves with identical ctrl ->
// both halves come from the same source lane; invalid lanes keep self (identity).
#define DPP_U64_MAX(k, ctrl) { \
    unsigned int _lo = (unsigned int)(k), _hi = (unsigned int)((k) >> 32); \
    unsigned int _olo = (unsigned int)__builtin_amdgcn_update_dpp((int)_lo, (int)_lo, ctrl, 0xF, 0xF, false); \
    unsigned int _ohi = (unsigned int)__builtin_amdgcn_update_dpp((int)_hi, (int)_hi, ctrl, 0xF, 0xF, false); \
    unsigned long long _o = ((unsigned long long)_ohi << 32) | _olo; \
    if (_o > (k)) (k) = _o; }

// ---------------- FPS ----------------
// 4 waves (256 thr), 16 pts/lane register-resident (global-provenance loads +
// per-iter pin; round-4 proved residency works this way). Key insight from the
// 4/8/16-wave scaling data: per-iter cost tracks LDS-pipe ops of the cross-wave
// reduce. So: pack (dist,idx) into ONE uint64 (bits(d)<<32 | ~idx) -- unsigned
// max == (dist desc, idx asc) lexicographic, bit-identical selection -- reduce
// via 6 DPP steps, lane63 writes one b64 slot, everyone reads 4 slots with two
// b128 reads. 16 LDS wave-ops/iter total (was ~150).
__global__ __launch_bounds__(FPS_T, 1) void fps_kernel(const float* __restrict__ xyz,
                                                       int* __restrict__ fps_idx,
                                                       float* __restrict__ out_xyz) {
#pragma clang fp contract(off)
    __shared__ float4 pxyz[N_];
    __shared__ int    sel[M_];
    __shared__ __align__(16) unsigned long long slotk[2][4];
    int b = blockIdx.x, t = threadIdx.x;
    const float* xb = xyz + (size_t)b * N_ * 3;
    float lx[FPS_PTS], ly[FPS_PTS], lz[FPS_PTS], dl[FPS_PTS];
#pragma unroll
    for (int j = 0; j < FPS_PTS; j++) {
        int i = (j << 8) + t;
        float x = xb[3*i], y = xb[3*i+1], z = xb[3*i+2];
        lx[j] = x; ly[j] = y; lz[j] = z;
        dl[j] = __builtin_inff();
        pxyz[i] = make_float4(x, y, z, 0.f);
    }
    __syncthreads();
    int wid = t >> 6, lane = t & 63;
    int cur = 0;
    float4 cc = pxyz[0];
    for (int k = 0; k < M_; k++) {
        float cx = cc.x, cy = cc.y, cz = cc.z;
        if (t == 0) sel[k] = cur;
#pragma unroll
        for (int j = 0; j < FPS_PTS; j++)
            asm volatile("" : "+v"(lx[j]), "+v"(ly[j]), "+v"(lz[j]));
        float bv = -1.0f; int bi = 0x7fffffff;
#pragma unroll
        for (int j = 0; j < FPS_PTS; j++) {
            float dx = lx[j] - cx, dy = ly[j] - cy, dz = lz[j] - cz;
            float t0 = dx*dx, t1 = dy*dy, t2 = dz*dz;
            float d = (t0 + t1) + t2;
            float od = dl[j];
            float nd = d < od ? d : od;
            dl[j] = nd;
            if (nd > bv) { bv = nd; bi = (j << 8) + t; }  // strict > keeps smallest idx per lane
        }
        // packed key: dist bits (non-negative -> monotonic) desc, then idx asc
        unsigned long long key = ((unsigned long long)__float_as_uint(bv) << 32)
                               | (unsigned int)(~bi);
        DPP_U64_MAX(key, 0x111);  // row_shr:1
        DPP_U64_MAX(key, 0x112);  // row_shr:2
        DPP_U64_MAX(key, 0x114);  // row_shr:4
        DPP_U64_MAX(key, 0x118);  // row_shr:8
        DPP_U64_MAX(key, 0x142);  // row_bcast:15
        DPP_U64_MAX(key, 0x143);  // row_bcast:31 -> lane63 holds wave max
        int p = k & 1;
        if (lane == 63) slotk[p][wid] = key;
        __syncthreads();
        ulonglong2 s01 = *(const ulonglong2*)&slotk[p][0];
        ulonglong2 s23 = *(const ulonglong2*)&slotk[p][2];
        unsigned long long kk = s01.x;
        if (s01.y > kk) kk = s01.y;
        if (s23.x > kk) kk = s23.x;
        if (s23.y > kk) kk = s23.y;
        cur = (int)(~(unsigned int)kk);
        cc = pxyz[cur];   // single uniform ds_read_b128
        // no 2nd barrier: iter k+1 writes buffer (k+1)&1; its previous readers
        // (iter k-1) are separated by iter k's barrier.
    }
    __syncthreads();
    for (int i = t; i < M_; i += FPS_T) {
        int ix = sel[i];
        float4 q = pxyz[ix];
        fps_idx[b*M_ + i] = ix;
        out_xyz[(b*M_ + i)*3 + 0] = q.x;
        out_xyz[(b*M_ + i)*3 + 1] = q.y;
        out_xyz[(b*M_ + i)*3 + 2] = q.z;
    }
}

// ---------------- Ball query ---------------- (unchanged, proven)
__global__ __launch_bounds__(256) void ballq_kernel(const float* __restrict__ xyz,
                                                    const int* __restrict__ fps_idx,
                                                    int* __restrict__ ball_idx) {
#pragma clang fp contract(off)
    __shared__ float cd[CAP];
    __shared__ int   ci[CAP];
    __shared__ int   cnt;
    __shared__ float rv[4];
    __shared__ int   ri[4];
    __shared__ int   slots[33];
    int blk = blockIdx.x;
    int b = blk >> 10, m = blk & (M_ - 1);
    int t = threadIdx.x;
    if (t == 0) cnt = 0;
    __syncthreads();
    const float* xb = xyz + (size_t)b * N_ * 3;
    int cidx = fps_idx[b*M_ + m];
    float cx = xb[cidx*3+0], cy = xb[cidx*3+1], cz = xb[cidx*3+2];
    float bv = 3.4e38f; int bi = 0x7fffffff;
    for (int i = t; i < N_; i += 256) {
        float dx = xb[i*3+0] - cx, dy = xb[i*3+1] - cy, dz = xb[i*3+2] - cz;
        float t0 = dx*dx, t1 = dy*dy, t2 = dz*dz;
        float d = (t0 + t1) + t2;
        if (d < bv || (d == bv && i < bi)) { bv = d; bi = i; }
        if (d <= R2) {
            int p = atomicAdd(&cnt, 1);
            if (p < CAP) { cd[p] = d; ci[p] = i; }
        }
    }
    for (int off = 32; off >= 1; off >>= 1) {
        float ov = __shfl_xor(bv, off, 64);
        int   oi = __shfl_xor(bi, off, 64);
        if (ov < bv || (ov == bv && oi < bi)) { bv = ov; bi = oi; }
    }
    int w = t >> 6;
    if ((t & 63) == 0) { rv[w] = bv; ri[w] = bi; }
    __syncthreads();
    int n = cnt < CAP ? cnt : CAP;
    for (int j = t; j < n; j += 256) {
        float dj = cd[j]; int ij = ci[j];
        int rank = 0;
        for (int k = 0; k < n; k++) {
            float dk = cd[k]; int ik = ci[k];
            rank += (dk < dj) || (dk == dj && ik < ij);
        }
        if (rank < S_) slots[rank] = ij;
    }
    if (t == 0) {
        float v = rv[0]; int ix = ri[0];
        for (int j = 1; j < 4; j++)
            if (rv[j] < v || (rv[j] == v && ri[j] < ix)) { v = rv[j]; ix = ri[j]; }
        slots[32] = ix;
    }
    __syncthreads();
    if (t < S_) {
        int nearest = (n > 0) ? slots[0] : slots[32];
        int ix = (t < n) ? slots[t] : nearest;
        ball_idx[(size_t)(b*M_ + m)*S_ + t] = ix;
    }
}

// uniform-broadcast float4 dot, weight row in registers; order = c ascending
// (same accumulation order as the validated scalar loop; compiler contracts to
// the same fma chain; padded tail contributes exact +0).
template<int STEPS>
__device__ __forceinline__ float dot4u(const float4* __restrict__ x4,
                                       const float (&wr)[STEPS*4], float acc) {
#pragma unroll
    for (int c4 = 0; c4 < STEPS; c4++) {
        float4 v = x4[c4];
        acc += v.x * wr[4*c4+0];
        acc += v.y * wr[4*c4+1];
        acc += v.z * wr[4*c4+2];
        acc += v.w * wr[4*c4+3];
    }
    return acc;
}

// ---------------- MLP chain (4-pass, fast inner loops) ----------------
// MODE: 0=stats L0, 1=stats L1, 2=stats L2, 3=final out.
// Each block computes the needed BN coefs locally from the global stats
// buckets (finalize folded in; kernels removed).
// stats bucket layout: [sum0 64 | sq0 64 | sum1 64 | sq1 64 | sum2 128 | sq2 128]
template<int MODE>
__global__ __launch_bounds__(256) void mlp_kernel(
    const float* __restrict__ xyz, const float* __restrict__ feat,
    const int* __restrict__ fps_idx, const int* __restrict__ ball_idx,
    const float* __restrict__ w0, const float* __restrict__ b0,
    const float* __restrict__ g0, const float* __restrict__ be0,
    const float* __restrict__ w1, const float* __restrict__ b1,
    const float* __restrict__ g1, const float* __restrict__ be1,
    const float* __restrict__ w2, const float* __restrict__ b2,
    const float* __restrict__ g2, const float* __restrict__ be2,
    float* __restrict__ stats, float* __restrict__ out_feat) {
    __shared__ __align__(16) float xs[S_][68];   // padded: col 67 = 0
    __shared__ __align__(16) float y0s[S_][C0];
    __shared__ __align__(16) float y1s[S_][C1];
    __shared__ float red[256], red2[256];
    __shared__ float lc[512];                    // [a0 64|c0 64|a1 64|c1 64|a2 128|c2 128]
    __shared__ int idxs[S_];
    int blk = blockIdx.x;
    int b = blk >> 10, m = blk & (M_ - 1);
    int t = threadIdx.x;
    const float inv_n = 1.0f / (float)NTOT;
    // ---- local BN coefs from stats buckets (redundant per block, deterministic)
    if (MODE >= 1 && t < 64) {
        float s = 0.f, s2 = 0.f;
        for (int j = 0; j < NBUCK; j++) { s += stats[j*512 + t]; s2 += stats[j*512 + 64 + t]; }
        float mean = s * inv_n, var = s2 * inv_n - mean * mean;
        float a = g0[t] * (1.0f / sqrtf(var + 1e-5f));
        lc[t] = a; lc[64 + t] = be0[t] - mean * a;
    }
    if (MODE >= 2 && t < 64) {
        float s = 0.f, s2 = 0.f;
        for (int j = 0; j < NBUCK; j++) { s += stats[j*512 + 128 + t]; s2 += stats[j*512 + 192 + t]; }
        float mean = s * inv_n, var = s2 * inv_n - mean * mean;
        float a = g1[t] * (1.0f / sqrtf(var + 1e-5f));
        lc[128 + t] = a; lc[192 + t] = be1[t] - mean * a;
    }
    if (MODE == 3 && t < 128) {
        float s = 0.f, s2 = 0.f;
        for (int j = 0; j < NBUCK; j++) { s += stats[j*512 + 256 + t]; s2 += stats[j*512 + 384 + t]; }
        float mean = s * inv_n, var = s2 * inv_n - mean * mean;
        float a = g2[t] * (1.0f / sqrtf(var + 1e-5f));
        lc[256 + t] = a; lc[384 + t] = be2[t] - mean * a;
    }
    // ---- gather x = [grouped_xyz(3) | grouped_feat(64) | 0-pad]
    const float* xb = xyz + (size_t)b * N_ * 3;
    int cidx = fps_idx[b*M_ + m];
    float cx = xb[cidx*3+0], cy = xb[cidx*3+1], cz = xb[cidx*3+2];
    if (t < S_) idxs[t] = ball_idx[(size_t)blk * S_ + t];
    __syncthreads();
    for (int i = t; i < S_*68; i += 256) {
        int s = i / 68, c = i - s * 68;
        int p = idxs[s];
        float v;
        if (c == 0)       v = xb[p*3+0] - cx;
        else if (c == 1)  v = xb[p*3+1] - cy;
        else if (c == 2)  v = xb[p*3+2] - cz;
        else if (c == 67) v = 0.f;
        else              v = feat[((size_t)b*N_ + p)*IN_ + (c - 3)];
        xs[s][c] = v;
    }
    __syncthreads();
    // ---- layer 0: 67 -> 64 (weight row in regs, wr[67]=0 pad)
    {
        int d = t & 63;
        float wr[68];
        {
            const float* w = w0 + d * C0IN;
#pragma unroll
            for (int c = 0; c < C0IN; c++) wr[c] = w[c];
            wr[67] = 0.f;
        }
        float bias = b0[d];
        float lsum = 0.f, lsq = 0.f;
#pragma unroll
        for (int q = 0; q < 8; q++) {
            int s = (t >> 6) + q * 4;
            float acc = dot4u<17>((const float4*)&xs[s][0], wr, bias);
            if (MODE == 0) { lsum += acc; lsq += acc * acc; }
            else {
                float v = acc * lc[d] + lc[64 + d];
                y0s[s][d] = v > 0.f ? v : 0.f;
            }
        }
        if (MODE == 0) {
            red[t] = lsum; red2[t] = lsq;
            __syncthreads();
            if (t < 64) {
                float* sb = stats + (size_t)(blk & (NBUCK-1)) * 512;
                atomicAdd(&sb[t],      red[t]  + red[t+64]  + red[t+128]  + red[t+192]);
                atomicAdd(&sb[64 + t], red2[t] + red2[t+64] + red2[t+128] + red2[t+192]);
            }
            return;
        }
    }
    __syncthreads();
    // ---- layer 1: 64 -> 64
    {
        int d = t & 63;
        float wr[64];
        {
            const float* w = w1 + d * C0;
#pragma unroll
            for (int c = 0; c < C0; c++) wr[c] = w[c];
        }
        float bias = b1[d];
        float lsum = 0.f, lsq = 0.f;
#pragma unroll
        for (int q = 0; q < 8; q++) {
            int s = (t >> 6) + q * 4;
            float acc = dot4u<16>((const float4*)&y0s[s][0], wr, bias);
            if (MODE == 1) { lsum += acc; lsq += acc * acc; }
            else {
                float v = acc * lc[128 + d] + lc[192 + d];
                y1s[s][d] = v > 0.f ? v : 0.f;
            }
        }
        if (MODE == 1) {
            red[t] = lsum; red2[t] = lsq;
            __syncthreads();
            if (t < 64) {
                float* sb = stats + (size_t)(blk & (NBUCK-1)) * 512;
                atomicAdd(&sb[128 + t], red[t]  + red[t+64]  + red[t+128]  + red[t+192]);
                atomicAdd(&sb[192 + t], red2[t] + red2[t+64] + red2[t+128] + red2[t+192]);
            }
            return;
        }
    }
    __syncthreads();
    // ---- layer 2: 64 -> 128
    {
        int d = t & 127;
        float wr[64];
        {
            const float* w = w2 + d * C1;
#pragma unroll
            for (int c = 0; c < C1; c++) wr[c] = w[c];
        }
        float bias = b2[d];
        float lsum = 0.f, lsq = 0.f, lmax = -3.4e38f;
#pragma unroll
        for (int q = 0; q < 16; q++) {
            int s = (t >> 7) + q * 2;
            float acc = dot4u<16>((const float4*)&y1s[s][0], wr, bias);
            if (MODE == 2) { lsum += acc; lsq += acc * acc; }
            else {
                float v = acc * lc[256 + d] + lc[384 + d];
                v = v > 0.f ? v : 0.f;
                lmax = v > lmax ? v : lmax;
            }
        }
        if (MODE == 2) {
            red[t] = lsum; red2[t] = lsq;
            __syncthreads();
            if (t < 128) {
                float* sb = stats + (size_t)(blk & (NBUCK-1)) * 512;
                atomicAdd(&sb[256 + t], red[t]  + red[t+128]);
                atomicAdd(&sb[384 + t], red2[t] + red2[t+128]);
            }
            return;
        }
        red[t] = lmax;
        __syncthreads();
        if (t < 128) {
            float v = red[t] > red[t+128] ? red[t] : red[t+128];
            out_feat[(size_t)blk * C2 + t] = v;
        }
    }
}

extern "C" void kernel_launch(void* const* d_in, const int* in_sizes, int n_in,
                              void* d_out, int out_size, void* d_ws, size_t ws_size,
                              hipStream_t stream) {
    const float* xyz  = (const float*)d_in[0];
    const float* feat = (const float*)d_in[1];
    const float* w0 = (const float*)d_in[2];  const float* b0 = (const float*)d_in[3];
    const float* g0 = (const float*)d_in[4];  const float* be0 = (const float*)d_in[5];
    const float* w1 = (const float*)d_in[6];  const float* b1 = (const float*)d_in[7];
    const float* g1 = (const float*)d_in[8];  const float* be1 = (const float*)d_in[9];
    const float* w2 = (const float*)d_in[10]; const float* b2 = (const float*)d_in[11];
    const float* g2 = (const float*)d_in[12]; const float* be2 = (const float*)d_in[13];
    float* out_xyz  = (float*)d_out;
    float* out_feat = out_xyz + B_*M_*3;

    int* fps_i  = (int*)d_ws;                                   // 64 KB
    int* ball_i = (int*)((char*)d_ws + 65536);                  // 2 MB
    float* stats = (float*)((char*)d_ws + 65536 + 2097152);     // NBUCK*512*4 = 32 KB

    hipMemsetAsync(stats, 0, NBUCK*512*sizeof(float), stream);
    fps_kernel<<<B_, FPS_T, 0, stream>>>(xyz, fps_i, out_xyz);
    ballq_kernel<<<B_*M_, 256, 0, stream>>>(xyz, fps_i, ball_i);
    mlp_kernel<0><<<B_*M_, 256, 0, stream>>>(xyz, feat, fps_i, ball_i,
        w0, b0, g0, be0, w1, b1, g1, be1, w2, b2, g2, be2, stats, out_feat);
    mlp_kernel<1><<<B_*M_, 256, 0, stream>>>(xyz, feat, fps_i, ball_i,
        w0, b0, g0, be0, w1, b1, g1, be1, w2, b2, g2, be2, stats, out_feat);
    mlp_kernel<2><<<B_*M_, 256, 0, stream>>>(xyz, feat, fps_i, ball_i,
        w0, b0, g0, be0, w1, b1, g1, be1, w2, b2, g2, be2, stats, out_feat);
    mlp_kernel<3><<<B_*M_, 256, 0, stream>>>(xyz, feat, fps_i, ball_i,
        w0, b0, g0, be0, w1, b1, g1, be1, w2, b2, g2, be2, stats, out_feat);
}

// Round 6
// 1998.640 us; speedup vs baseline: 1.5258x; 1.3318x over previous
//
#include <hip/hip_runtime.h>

#define B_ 16
#define N_ 4096
#define M_ 1024
#define S_ 32
#define IN_ 64
#define C0IN 67
#define C0 64
#define C1 64
#define C2 128
#define NTOT (B_*M_*S_)
#define R2 0.04f
#define CAP 1024
#define NBUCK 16

#define FPS_T 256
#define FPS_PTS 16   // 4096 / 256

// 64-bit DPP max (packed key). Two 32-bit DPP moves with identical ctrl ->
// both halves come from the same source lane; invalid lanes keep self (identity).
#define DPP_U64_MAX(k, ctrl) { \
    unsigned int _lo = (unsigned int)(k), _hi = (unsigned int)((k) >> 32); \
    unsigned int _olo = (unsigned int)__builtin_amdgcn_update_dpp((int)_lo, (int)_lo, ctrl, 0xF, 0xF, false); \
    unsigned int _ohi = (unsigned int)__builtin_amdgcn_update_dpp((int)_hi, (int)_hi, ctrl, 0xF, 0xF, false); \
    unsigned long long _o = ((unsigned long long)_ohi << 32) | _olo; \
    if (_o > (k)) (k) = _o; }

// ---------------- FPS ---------------- (unchanged, proven round 5)
__global__ __launch_bounds__(FPS_T, 1) void fps_kernel(const float* __restrict__ xyz,
                                                       int* __restrict__ fps_idx,
                                                       float* __restrict__ out_xyz) {
#pragma clang fp contract(off)
    __shared__ float4 pxyz[N_];
    __shared__ int    sel[M_];
    __shared__ __align__(16) unsigned long long slotk[2][4];
    int b = blockIdx.x, t = threadIdx.x;
    const float* xb = xyz + (size_t)b * N_ * 3;
    float lx[FPS_PTS], ly[FPS_PTS], lz[FPS_PTS], dl[FPS_PTS];
#pragma unroll
    for (int j = 0; j < FPS_PTS; j++) {
        int i = (j << 8) + t;
        float x = xb[3*i], y = xb[3*i+1], z = xb[3*i+2];
        lx[j] = x; ly[j] = y; lz[j] = z;
        dl[j] = __builtin_inff();
        pxyz[i] = make_float4(x, y, z, 0.f);
    }
    __syncthreads();
    int wid = t >> 6, lane = t & 63;
    int cur = 0;
    float4 cc = pxyz[0];
    for (int k = 0; k < M_; k++) {
        float cx = cc.x, cy = cc.y, cz = cc.z;
        if (t == 0) sel[k] = cur;
#pragma unroll
        for (int j = 0; j < FPS_PTS; j++)
            asm volatile("" : "+v"(lx[j]), "+v"(ly[j]), "+v"(lz[j]));
        float bv = -1.0f; int bi = 0x7fffffff;
#pragma unroll
        for (int j = 0; j < FPS_PTS; j++) {
            float dx = lx[j] - cx, dy = ly[j] - cy, dz = lz[j] - cz;
            float t0 = dx*dx, t1 = dy*dy, t2 = dz*dz;
            float d = (t0 + t1) + t2;
            float od = dl[j];
            float nd = d < od ? d : od;
            dl[j] = nd;
            if (nd > bv) { bv = nd; bi = (j << 8) + t; }
        }
        unsigned long long key = ((unsigned long long)__float_as_uint(bv) << 32)
                               | (unsigned int)(~bi);
        DPP_U64_MAX(key, 0x111);
        DPP_U64_MAX(key, 0x112);
        DPP_U64_MAX(key, 0x114);
        DPP_U64_MAX(key, 0x118);
        DPP_U64_MAX(key, 0x142);
        DPP_U64_MAX(key, 0x143);
        int p = k & 1;
        if (lane == 63) slotk[p][wid] = key;
        __syncthreads();
        ulonglong2 s01 = *(const ulonglong2*)&slotk[p][0];
        ulonglong2 s23 = *(const ulonglong2*)&slotk[p][2];
        unsigned long long kk = s01.x;
        if (s01.y > kk) kk = s01.y;
        if (s23.x > kk) kk = s23.x;
        if (s23.y > kk) kk = s23.y;
        cur = (int)(~(unsigned int)kk);
        cc = pxyz[cur];
    }
    __syncthreads();
    for (int i = t; i < M_; i += FPS_T) {
        int ix = sel[i];
        float4 q = pxyz[ix];
        fps_idx[b*M_ + i] = ix;
        out_xyz[(b*M_ + i)*3 + 0] = q.x;
        out_xyz[(b*M_ + i)*3 + 1] = q.y;
        out_xyz[(b*M_ + i)*3 + 2] = q.z;
    }
}

// ---------------- Ball query ---------------- (unchanged, proven)
__global__ __launch_bounds__(256) void ballq_kernel(const float* __restrict__ xyz,
                                                    const int* __restrict__ fps_idx,
                                                    int* __restrict__ ball_idx) {
#pragma clang fp contract(off)
    __shared__ float cd[CAP];
    __shared__ int   ci[CAP];
    __shared__ int   cnt;
    __shared__ float rv[4];
    __shared__ int   ri[4];
    __shared__ int   slots[33];
    int blk = blockIdx.x;
    int b = blk >> 10, m = blk & (M_ - 1);
    int t = threadIdx.x;
    if (t == 0) cnt = 0;
    __syncthreads();
    const float* xb = xyz + (size_t)b * N_ * 3;
    int cidx = fps_idx[b*M_ + m];
    float cx = xb[cidx*3+0], cy = xb[cidx*3+1], cz = xb[cidx*3+2];
    float bv = 3.4e38f; int bi = 0x7fffffff;
    for (int i = t; i < N_; i += 256) {
        float dx = xb[i*3+0] - cx, dy = xb[i*3+1] - cy, dz = xb[i*3+2] - cz;
        float t0 = dx*dx, t1 = dy*dy, t2 = dz*dz;
        float d = (t0 + t1) + t2;
        if (d < bv || (d == bv && i < bi)) { bv = d; bi = i; }
        if (d <= R2) {
            int p = atomicAdd(&cnt, 1);
            if (p < CAP) { cd[p] = d; ci[p] = i; }
        }
    }
    for (int off = 32; off >= 1; off >>= 1) {
        float ov = __shfl_xor(bv, off, 64);
        int   oi = __shfl_xor(bi, off, 64);
        if (ov < bv || (ov == bv && oi < bi)) { bv = ov; bi = oi; }
    }
    int w = t >> 6;
    if ((t & 63) == 0) { rv[w] = bv; ri[w] = bi; }
    __syncthreads();
    int n = cnt < CAP ? cnt : CAP;
    for (int j = t; j < n; j += 256) {
        float dj = cd[j]; int ij = ci[j];
        int rank = 0;
        for (int k = 0; k < n; k++) {
            float dk = cd[k]; int ik = ci[k];
            rank += (dk < dj) || (dk == dj && ik < ij);
        }
        if (rank < S_) slots[rank] = ij;
    }
    if (t == 0) {
        float v = rv[0]; int ix = ri[0];
        for (int j = 1; j < 4; j++)
            if (rv[j] < v || (rv[j] == v && ri[j] < ix)) { v = rv[j]; ix = ri[j]; }
        slots[32] = ix;
    }
    __syncthreads();
    if (t < S_) {
        int nearest = (n > 0) ? slots[0] : slots[32];
        int ix = (t < n) ? slots[t] : nearest;
        ball_idx[(size_t)(b*M_ + m)*S_ + t] = ix;
    }
}

// uniform-broadcast float4 dot, weight row in registers; order = c ascending
template<int STEPS>
__device__ __forceinline__ float dot4u(const float4* __restrict__ x4,
                                       const float (&wr)[STEPS*4], float acc) {
#pragma unroll
    for (int c4 = 0; c4 < STEPS; c4++) {
        float4 v = x4[c4];
        acc += v.x * wr[4*c4+0];
        acc += v.y * wr[4*c4+1];
        acc += v.z * wr[4*c4+2];
        acc += v.w * wr[4*c4+3];
    }
    return acc;
}

// ============ Staged pipeline (ws >= ~137 MB): each layer computed once ============
// zbuf: 2048 floats per center. P1 writes z0; P2 reads z0, writes z1 IN-PLACE
// (each thread reads its own addresses into regs before writing the same
// addresses -- bijective mapping, no cross-thread hazard); P3/P4 read z1.
// stats bucket layout (NBUCK x 512): [sum0 64|sq0 64|sum1 64|sq1 64|sum2 128|sq2 128]

// P1: gather + L0 -> z0, stats0
__global__ __launch_bounds__(256) void mlpS1_kernel(
    const float* __restrict__ xyz, const float* __restrict__ feat,
    const int* __restrict__ fps_idx, const int* __restrict__ ball_idx,
    const float* __restrict__ w0, const float* __restrict__ b0,
    float* __restrict__ zbuf, float* __restrict__ stats) {
    __shared__ __align__(16) float xs[S_][68];   // padded: col 67 = 0
    __shared__ float red[256], red2[256];
    __shared__ int idxs[S_];
    int blk = blockIdx.x, b = blk >> 10, m = blk & (M_ - 1), t = threadIdx.x;
    const float* xb = xyz + (size_t)b * N_ * 3;
    int cidx = fps_idx[b*M_ + m];
    float cx = xb[cidx*3+0], cy = xb[cidx*3+1], cz = xb[cidx*3+2];
    if (t < S_) idxs[t] = ball_idx[(size_t)blk * S_ + t];
    __syncthreads();
    for (int i = t; i < S_*68; i += 256) {
        int s = i / 68, c = i - s * 68;
        int p = idxs[s];
        float v;
        if (c == 0)       v = xb[p*3+0] - cx;
        else if (c == 1)  v = xb[p*3+1] - cy;
        else if (c == 2)  v = xb[p*3+2] - cz;
        else if (c == 67) v = 0.f;
        else              v = feat[((size_t)b*N_ + p)*IN_ + (c - 3)];
        xs[s][c] = v;
    }
    __syncthreads();
    int d = t & 63;
    float wr[68];
    {
        const float* w = w0 + d * C0IN;
#pragma unroll
        for (int c = 0; c < C0IN; c++) wr[c] = w[c];
        wr[67] = 0.f;
    }
    float bias = b0[d];
    float lsum = 0.f, lsq = 0.f;
    float* zt = zbuf + (size_t)blk * 2048;
#pragma unroll
    for (int q = 0; q < 8; q++) {
        int s = (t >> 6) + q * 4;
        float acc = dot4u<17>((const float4*)&xs[s][0], wr, bias);
        zt[s*64 + d] = acc;              // = zt[t + 256q], coalesced
        lsum += acc; lsq += acc * acc;
    }
    red[t] = lsum; red2[t] = lsq;
    __syncthreads();
    if (t < 64) {
        float* sb = stats + (size_t)(blk & (NBUCK-1)) * 512;
        atomicAdd(&sb[t],      red[t]  + red[t+64]  + red[t+128]  + red[t+192]);
        atomicAdd(&sb[64 + t], red2[t] + red2[t+64] + red2[t+128] + red2[t+192]);
    }
}

// P2: z0 -> BN0+relu -> L1 -> z1 (in-place), stats1
__global__ __launch_bounds__(256) void mlpS2_kernel(
    float* __restrict__ zbuf,
    const float* __restrict__ w1, const float* __restrict__ b1,
    const float* __restrict__ g0, const float* __restrict__ be0,
    float* __restrict__ stats) {
    __shared__ __align__(16) float y0s[S_][C0];
    __shared__ float red[256], red2[256];
    __shared__ float lc[128];
    int blk = blockIdx.x, t = threadIdx.x;
    const float inv_n = 1.0f / (float)NTOT;
    if (t < 64) {
        float s = 0.f, s2 = 0.f;
        for (int j = 0; j < NBUCK; j++) { s += stats[j*512 + t]; s2 += stats[j*512 + 64 + t]; }
        float mean = s * inv_n, var = s2 * inv_n - mean * mean;
        float a = g0[t] * (1.0f / sqrtf(var + 1e-5f));
        lc[t] = a; lc[64 + t] = be0[t] - mean * a;
    }
    int d = t & 63;
    float* zt = zbuf + (size_t)blk * 2048;
    float zv[8];
#pragma unroll
    for (int j = 0; j < 8; j++) zv[j] = zt[t + 256*j];   // channel d const across j
    float wr[64];
    {
        const float* w = w1 + d * C0;
#pragma unroll
        for (int c = 0; c < C0; c++) wr[c] = w[c];
    }
    float bias = b1[d];
    __syncthreads();   // lc ready
    float a0 = lc[d], c0 = lc[64 + d];
#pragma unroll
    for (int j = 0; j < 8; j++) {
        float v = zv[j] * a0 + c0;
        y0s[(t >> 6) + 4*j][d] = v > 0.f ? v : 0.f;
    }
    __syncthreads();   // y0s ready
    float lsum = 0.f, lsq = 0.f;
#pragma unroll
    for (int q = 0; q < 8; q++) {
        int s = (t >> 6) + q * 4;
        float acc = dot4u<16>((const float4*)&y0s[s][0], wr, bias);
        zt[s*64 + d] = acc;              // overwrite own read addresses (safe)
        lsum += acc; lsq += acc * acc;
    }
    red[t] = lsum; red2[t] = lsq;
    __syncthreads();
    if (t < 64) {
        float* sb = stats + (size_t)(blk & (NBUCK-1)) * 512;
        atomicAdd(&sb[128 + t], red[t]  + red[t+64]  + red[t+128]  + red[t+192]);
        atomicAdd(&sb[192 + t], red2[t] + red2[t+64] + red2[t+128] + red2[t+192]);
    }
}

// P3: z1 -> BN1+relu -> L2 -> stats2 (no store)
__global__ __launch_bounds__(256) void mlpS3_kernel(
    const float* __restrict__ zbuf,
    const float* __restrict__ w2, const float* __restrict__ b2,
    const float* __restrict__ g1, const float* __restrict__ be1,
    float* __restrict__ stats) {
    __shared__ __align__(16) float y1s[S_][C1];
    __shared__ float red[256], red2[256];
    __shared__ float lc[128];
    int blk = blockIdx.x, t = threadIdx.x;
    const float inv_n = 1.0f / (float)NTOT;
    if (t < 64) {
        float s = 0.f, s2 = 0.f;
        for (int j = 0; j < NBUCK; j++) { s += stats[j*512 + 128 + t]; s2 += stats[j*512 + 192 + t]; }
        float mean = s * inv_n, var = s2 * inv_n - mean * mean;
        float a = g1[t] * (1.0f / sqrtf(var + 1e-5f));
        lc[t] = a; lc[64 + t] = be1[t] - mean * a;
    }
    int dn = t & 63;
    const float* zt = zbuf + (size_t)blk * 2048;
    float zv[8];
#pragma unroll
    for (int j = 0; j < 8; j++) zv[j] = zt[t + 256*j];
    int d = t & 127;
    float wr[64];
    {
        const float* w = w2 + d * C1;
#pragma unroll
        for (int c = 0; c < C1; c++) wr[c] = w[c];
    }
    float bias = b2[d];
    __syncthreads();
    float a1 = lc[dn], c1 = lc[64 + dn];
#pragma unroll
    for (int j = 0; j < 8; j++) {
        float v = zv[j] * a1 + c1;
        y1s[(t >> 6) + 4*j][dn] = v > 0.f ? v : 0.f;
    }
    __syncthreads();
    float lsum = 0.f, lsq = 0.f;
#pragma unroll
    for (int q = 0; q < 16; q++) {
        int s = (t >> 7) + q * 2;
        float acc = dot4u<16>((const float4*)&y1s[s][0], wr, bias);
        lsum += acc; lsq += acc * acc;
    }
    red[t] = lsum; red2[t] = lsq;
    __syncthreads();
    if (t < 128) {
        float* sb = stats + (size_t)(blk & (NBUCK-1)) * 512;
        atomicAdd(&sb[256 + t], red[t]  + red[t+128]);
        atomicAdd(&sb[384 + t], red2[t] + red2[t+128]);
    }
}

// P4: z1 -> BN1+relu -> L2 -> BN2+relu -> max -> out
__global__ __launch_bounds__(256) void mlpS4_kernel(
    const float* __restrict__ zbuf,
    const float* __restrict__ w2, const float* __restrict__ b2,
    const float* __restrict__ g1, const float* __restrict__ be1,
    const float* __restrict__ g2, const float* __restrict__ be2,
    const float* __restrict__ stats, float* __restrict__ out_feat) {
    __shared__ __align__(16) float y1s[S_][C1];
    __shared__ float red[256];
    __shared__ float lc[384];   // [a1 64|c1 64|a2 128|c2 128]
    int blk = blockIdx.x, t = threadIdx.x;
    const float inv_n = 1.0f / (float)NTOT;
    if (t < 64) {
        float s = 0.f, s2 = 0.f;
        for (int j = 0; j < NBUCK; j++) { s += stats[j*512 + 128 + t]; s2 += stats[j*512 + 192 + t]; }
        float mean = s * inv_n, var = s2 * inv_n - mean * mean;
        float a = g1[t] * (1.0f / sqrtf(var + 1e-5f));
        lc[t] = a; lc[64 + t] = be1[t] - mean * a;
    }
    if (t < 128) {
        float s = 0.f, s2 = 0.f;
        for (int j = 0; j < NBUCK; j++) { s += stats[j*512 + 256 + t]; s2 += stats[j*512 + 384 + t]; }
        float mean = s * inv_n, var = s2 * inv_n - mean * mean;
        float a = g2[t] * (1.0f / sqrtf(var + 1e-5f));
        lc[128 + t] = a; lc[256 + t] = be2[t] - mean * a;
    }
    int dn = t & 63;
    const float* zt = zbuf + (size_t)blk * 2048;
    float zv[8];
#pragma unroll
    for (int j = 0; j < 8; j++) zv[j] = zt[t + 256*j];
    int d = t & 127;
    float wr[64];
    {
        const float* w = w2 + d * C1;
#pragma unroll
        for (int c = 0; c < C1; c++) wr[c] = w[c];
    }
    float bias = b2[d];
    __syncthreads();
    float a1 = lc[dn], c1 = lc[64 + dn];
#pragma unroll
    for (int j = 0; j < 8; j++) {
        float v = zv[j] * a1 + c1;
        y1s[(t >> 6) + 4*j][dn] = v > 0.f ? v : 0.f;
    }
    __syncthreads();
    float a2 = lc[128 + d], c2 = lc[256 + d];
    float lmax = -3.4e38f;
#pragma unroll
    for (int q = 0; q < 16; q++) {
        int s = (t >> 7) + q * 2;
        float acc = dot4u<16>((const float4*)&y1s[s][0], wr, bias);
        float v = acc * a2 + c2;
        v = v > 0.f ? v : 0.f;
        lmax = v > lmax ? v : lmax;
    }
    red[t] = lmax;
    __syncthreads();
    if (t < 128) {
        float v = red[t] > red[t+128] ? red[t] : red[t+128];
        out_feat[(size_t)blk * C2 + t] = v;
    }
}

// ============ Fallback 4-pass MLP (exact round-5, proven) ============
template<int MODE>
__global__ __launch_bounds__(256) void mlp_kernel(
    const float* __restrict__ xyz, const float* __restrict__ feat,
    const int* __restrict__ fps_idx, const int* __restrict__ ball_idx,
    const float* __restrict__ w0, const float* __restrict__ b0,
    const float* __restrict__ g0, const float* __restrict__ be0,
    const float* __restrict__ w1, const float* __restrict__ b1,
    const float* __restrict__ g1, const float* __restrict__ be1,
    const float* __restrict__ w2, const float* __restrict__ b2,
    const float* __restrict__ g2, const float* __restrict__ be2,
    float* __restrict__ stats, float* __restrict__ out_feat) {
    __shared__ __align__(16) float xs[S_][68];
    __shared__ __align__(16) float y0s[S_][C0];
    __shared__ __align__(16) float y1s[S_][C1];
    __shared__ float red[256], red2[256];
    __shared__ float lc[512];
    __shared__ int idxs[S_];
    int blk = blockIdx.x;
    int b = blk >> 10, m = blk & (M_ - 1);
    int t = threadIdx.x;
    const float inv_n = 1.0f / (float)NTOT;
    if (MODE >= 1 && t < 64) {
        float s = 0.f, s2 = 0.f;
        for (int j = 0; j < NBUCK; j++) { s += stats[j*512 + t]; s2 += stats[j*512 + 64 + t]; }
        float mean = s * inv_n, var = s2 * inv_n - mean * mean;
        float a = g0[t] * (1.0f / sqrtf(var + 1e-5f));
        lc[t] = a; lc[64 + t] = be0[t] - mean * a;
    }
    if (MODE >= 2 && t < 64) {
        float s = 0.f, s2 = 0.f;
        for (int j = 0; j < NBUCK; j++) { s += stats[j*512 + 128 + t]; s2 += stats[j*512 + 192 + t]; }
        float mean = s * inv_n, var = s2 * inv_n - mean * mean;
        float a = g1[t] * (1.0f / sqrtf(var + 1e-5f));
        lc[128 + t] = a; lc[192 + t] = be1[t] - mean * a;
    }
    if (MODE == 3 && t < 128) {
        float s = 0.f, s2 = 0.f;
        for (int j = 0; j < NBUCK; j++) { s += stats[j*512 + 256 + t]; s2 += stats[j*512 + 384 + t]; }
        float mean = s * inv_n, var = s2 * inv_n - mean * mean;
        float a = g2[t] * (1.0f / sqrtf(var + 1e-5f));
        lc[256 + t] = a; lc[384 + t] = be2[t] - mean * a;
    }
    const float* xb = xyz + (size_t)b * N_ * 3;
    int cidx = fps_idx[b*M_ + m];
    float cx = xb[cidx*3+0], cy = xb[cidx*3+1], cz = xb[cidx*3+2];
    if (t < S_) idxs[t] = ball_idx[(size_t)blk * S_ + t];
    __syncthreads();
    for (int i = t; i < S_*68; i += 256) {
        int s = i / 68, c = i - s * 68;
        int p = idxs[s];
        float v;
        if (c == 0)       v = xb[p*3+0] - cx;
        else if (c == 1)  v = xb[p*3+1] - cy;
        else if (c == 2)  v = xb[p*3+2] - cz;
        else if (c == 67) v = 0.f;
        else              v = feat[((size_t)b*N_ + p)*IN_ + (c - 3)];
        xs[s][c] = v;
    }
    __syncthreads();
    {
        int d = t & 63;
        float wr[68];
        {
            const float* w = w0 + d * C0IN;
#pragma unroll
            for (int c = 0; c < C0IN; c++) wr[c] = w[c];
            wr[67] = 0.f;
        }
        float bias = b0[d];
        float lsum = 0.f, lsq = 0.f;
#pragma unroll
        for (int q = 0; q < 8; q++) {
            int s = (t >> 6) + q * 4;
            float acc = dot4u<17>((const float4*)&xs[s][0], wr, bias);
            if (MODE == 0) { lsum += acc; lsq += acc * acc; }
            else {
                float v = acc * lc[d] + lc[64 + d];
                y0s[s][d] = v > 0.f ? v : 0.f;
            }
        }
        if (MODE == 0) {
            red[t] = lsum; red2[t] = lsq;
            __syncthreads();
            if (t < 64) {
                float* sb = stats + (size_t)(blk & (NBUCK-1)) * 512;
                atomicAdd(&sb[t],      red[t]  + red[t+64]  + red[t+128]  + red[t+192]);
                atomicAdd(&sb[64 + t], red2[t] + red2[t+64] + red2[t+128] + red2[t+192]);
            }
            return;
        }
    }
    __syncthreads();
    {
        int d = t & 63;
        float wr[64];
        {
            const float* w = w1 + d * C0;
#pragma unroll
            for (int c = 0; c < C0; c++) wr[c] = w[c];
        }
        float bias = b1[d];
        float lsum = 0.f, lsq = 0.f;
#pragma unroll
        for (int q = 0; q < 8; q++) {
            int s = (t >> 6) + q * 4;
            float acc = dot4u<16>((const float4*)&y0s[s][0], wr, bias);
            if (MODE == 1) { lsum += acc; lsq += acc * acc; }
            else {
                float v = acc * lc[128 + d] + lc[192 + d];
                y1s[s][d] = v > 0.f ? v : 0.f;
            }
        }
        if (MODE == 1) {
            red[t] = lsum; red2[t] = lsq;
            __syncthreads();
            if (t < 64) {
                float* sb = stats + (size_t)(blk & (NBUCK-1)) * 512;
                atomicAdd(&sb[128 + t], red[t]  + red[t+64]  + red[t+128]  + red[t+192]);
                atomicAdd(&sb[192 + t], red2[t] + red2[t+64] + red2[t+128] + red2[t+192]);
            }
            return;
        }
    }
    __syncthreads();
    {
        int d = t & 127;
        float wr[64];
        {
            const float* w = w2 + d * C1;
#pragma unroll
            for (int c = 0; c < C1; c++) wr[c] = w[c];
        }
        float bias = b2[d];
        float lsum = 0.f, lsq = 0.f, lmax = -3.4e38f;
#pragma unroll
        for (int q = 0; q < 16; q++) {
            int s = (t >> 7) + q * 2;
            float acc = dot4u<16>((const float4*)&y1s[s][0], wr, bias);
            if (MODE == 2) { lsum += acc; lsq += acc * acc; }
            else {
                float v = acc * lc[256 + d] + lc[384 + d];
                v = v > 0.f ? v : 0.f;
                lmax = v > lmax ? v : lmax;
            }
        }
        if (MODE == 2) {
            red[t] = lsum; red2[t] = lsq;
            __syncthreads();
            if (t < 128) {
                float* sb = stats + (size_t)(blk & (NBUCK-1)) * 512;
                atomicAdd(&sb[256 + t], red[t]  + red[t+128]);
                atomicAdd(&sb[384 + t], red2[t] + red2[t+128]);
            }
            return;
        }
        red[t] = lmax;
        __syncthreads();
        if (t < 128) {
            float v = red[t] > red[t+128] ? red[t] : red[t+128];
            out_feat[(size_t)blk * C2 + t] = v;
        }
    }
}

extern "C" void kernel_launch(void* const* d_in, const int* in_sizes, int n_in,
                              void* d_out, int out_size, void* d_ws, size_t ws_size,
                              hipStream_t stream) {
    const float* xyz  = (const float*)d_in[0];
    const float* feat = (const float*)d_in[1];
    const float* w0 = (const float*)d_in[2];  const float* b0 = (const float*)d_in[3];
    const float* g0 = (const float*)d_in[4];  const float* be0 = (const float*)d_in[5];
    const float* w1 = (const float*)d_in[6];  const float* b1 = (const float*)d_in[7];
    const float* g1 = (const float*)d_in[8];  const float* be1 = (const float*)d_in[9];
    const float* w2 = (const float*)d_in[10]; const float* b2 = (const float*)d_in[11];
    const float* g2 = (const float*)d_in[12]; const float* be2 = (const float*)d_in[13];
    float* out_xyz  = (float*)d_out;
    float* out_feat = out_xyz + B_*M_*3;

    int* fps_i  = (int*)d_ws;                                   // 64 KB
    int* ball_i = (int*)((char*)d_ws + 65536);                  // 2 MB
    float* stats = (float*)((char*)d_ws + 65536 + 2097152);     // NBUCK*512*4 = 32 KB
    size_t zoff = 65536 + 2097152 + (size_t)NBUCK*512*4;        // 256B-aligned
    float* zbuf = (float*)((char*)d_ws + zoff);                 // 16384*2048*4 = 128 MB
    size_t need = zoff + (size_t)B_*M_ * 2048 * 4;
    bool staged = ws_size >= need;

    hipMemsetAsync(stats, 0, NBUCK*512*sizeof(float), stream);
    fps_kernel<<<B_, FPS_T, 0, stream>>>(xyz, fps_i, out_xyz);
    ballq_kernel<<<B_*M_, 256, 0, stream>>>(xyz, fps_i, ball_i);

    if (staged) {
        mlpS1_kernel<<<B_*M_, 256, 0, stream>>>(xyz, feat, fps_i, ball_i, w0, b0, zbuf, stats);
        mlpS2_kernel<<<B_*M_, 256, 0, stream>>>(zbuf, w1, b1, g0, be0, stats);
        mlpS3_kernel<<<B_*M_, 256, 0, stream>>>(zbuf, w2, b2, g1, be1, stats);
        mlpS4_kernel<<<B_*M_, 256, 0, stream>>>(zbuf, w2, b2, g1, be1, g2, be2, stats, out_feat);
    } else {
        mlp_kernel<0><<<B_*M_, 256, 0, stream>>>(xyz, feat, fps_i, ball_i,
            w0, b0, g0, be0, w1, b1, g1, be1, w2, b2, g2, be2, stats, out_feat);
        mlp_kernel<1><<<B_*M_, 256, 0, stream>>>(xyz, feat, fps_i, ball_i,
            w0, b0, g0, be0, w1, b1, g1, be1, w2, b2, g2, be2, stats, out_feat);
        mlp_kernel<2><<<B_*M_, 256, 0, stream>>>(xyz, feat, fps_i, ball_i,
            w0, b0, g0, be0, w1, b1, g1, be1, w2, b2, g2, be2, stats, out_feat);
        mlp_kernel<3><<<B_*M_, 256, 0, stream>>>(xyz, feat, fps_i, ball_i,
            w0, b0, g0, be0, w1, b1, g1, be1, w2, b2, g2, be2, stats, out_feat);
    }
}

// Round 7
// 1883.117 us; speedup vs baseline: 1.6194x; 1.0613x over previous
//
#include <hip/hip_runtime.h>

#define B_ 16
#define N_ 4096
#define M_ 1024
#define S_ 32
#define IN_ 64
#define C0IN 67
#define C0 64
#define C1 64
#define C2 128
#define NTOT (B_*M_*S_)
#define R2 0.04f
#define CAP 1024
#define NBUCK 16
#define BQ_G 32   // centers per ball-query block

#define FPS_T 256
#define FPS_PTS 16   // 4096 / 256

// 64-bit DPP max (packed key). Two 32-bit DPP moves with identical ctrl ->
// both halves come from the same source lane; invalid lanes keep self (identity).
#define DPP_U64_MAX(k, ctrl) { \
    unsigned int _lo = (unsigned int)(k), _hi = (unsigned int)((k) >> 32); \
    unsigned int _olo = (unsigned int)__builtin_amdgcn_update_dpp((int)_lo, (int)_lo, ctrl, 0xF, 0xF, false); \
    unsigned int _ohi = (unsigned int)__builtin_amdgcn_update_dpp((int)_hi, (int)_hi, ctrl, 0xF, 0xF, false); \
    unsigned long long _o = ((unsigned long long)_ohi << 32) | _olo; \
    if (_o > (k)) (k) = _o; }

// ---------------- FPS ---------------- (unchanged, proven rounds 5-6: 663 us)
__global__ __launch_bounds__(FPS_T, 1) void fps_kernel(const float* __restrict__ xyz,
                                                       int* __restrict__ fps_idx,
                                                       float* __restrict__ out_xyz) {
#pragma clang fp contract(off)
    __shared__ float4 pxyz[N_];
    __shared__ int    sel[M_];
    __shared__ __align__(16) unsigned long long slotk[2][4];
    int b = blockIdx.x, t = threadIdx.x;
    const float* xb = xyz + (size_t)b * N_ * 3;
    float lx[FPS_PTS], ly[FPS_PTS], lz[FPS_PTS], dl[FPS_PTS];
#pragma unroll
    for (int j = 0; j < FPS_PTS; j++) {
        int i = (j << 8) + t;
        float x = xb[3*i], y = xb[3*i+1], z = xb[3*i+2];
        lx[j] = x; ly[j] = y; lz[j] = z;
        dl[j] = __builtin_inff();
        pxyz[i] = make_float4(x, y, z, 0.f);
    }
    __syncthreads();
    int wid = t >> 6, lane = t & 63;
    int cur = 0;
    float4 cc = pxyz[0];
    for (int k = 0; k < M_; k++) {
        float cx = cc.x, cy = cc.y, cz = cc.z;
        if (t == 0) sel[k] = cur;
#pragma unroll
        for (int j = 0; j < FPS_PTS; j++)
            asm volatile("" : "+v"(lx[j]), "+v"(ly[j]), "+v"(lz[j]));
        float bv = -1.0f; int bi = 0x7fffffff;
#pragma unroll
        for (int j = 0; j < FPS_PTS; j++) {
            float dx = lx[j] - cx, dy = ly[j] - cy, dz = lz[j] - cz;
            float t0 = dx*dx, t1 = dy*dy, t2 = dz*dz;
            float d = (t0 + t1) + t2;
            float od = dl[j];
            float nd = d < od ? d : od;
            dl[j] = nd;
            if (nd > bv) { bv = nd; bi = (j << 8) + t; }
        }
        unsigned long long key = ((unsigned long long)__float_as_uint(bv) << 32)
                               | (unsigned int)(~bi);
        DPP_U64_MAX(key, 0x111);
        DPP_U64_MAX(key, 0x112);
        DPP_U64_MAX(key, 0x114);
        DPP_U64_MAX(key, 0x118);
        DPP_U64_MAX(key, 0x142);
        DPP_U64_MAX(key, 0x143);
        int p = k & 1;
        if (lane == 63) slotk[p][wid] = key;
        __syncthreads();
        ulonglong2 s01 = *(const ulonglong2*)&slotk[p][0];
        ulonglong2 s23 = *(const ulonglong2*)&slotk[p][2];
        unsigned long long kk = s01.x;
        if (s01.y > kk) kk = s01.y;
        if (s23.x > kk) kk = s23.x;
        if (s23.y > kk) kk = s23.y;
        cur = (int)(~(unsigned int)kk);
        cc = pxyz[cur];
    }
    __syncthreads();
    for (int i = t; i < M_; i += FPS_T) {
        int ix = sel[i];
        float4 q = pxyz[ix];
        fps_idx[b*M_ + i] = ix;
        out_xyz[(b*M_ + i)*3 + 0] = q.x;
        out_xyz[(b*M_ + i)*3 + 1] = q.y;
        out_xyz[(b*M_ + i)*3 + 2] = q.z;
    }
}

// ---------------- Ball query (grouped) ----------------
// One block per (batch, 32-center group): xyz staged ONCE into LDS float4,
// then 32 centers scan LDS instead of re-reading global. Per-center logic is
// byte-identical to the proven single-center kernel (same candidate collect,
// same (d,idx) rank, same argmin fallback) -- only the coord source changed.
__global__ __launch_bounds__(256) void ballq_kernel(const float* __restrict__ xyz,
                                                    const int* __restrict__ fps_idx,
                                                    int* __restrict__ ball_idx) {
#pragma clang fp contract(off)
    __shared__ float4 pts[N_];     // 64 KB
    __shared__ float cd[CAP];
    __shared__ int   ci[CAP];
    __shared__ int   cnt;
    __shared__ float rv[4];
    __shared__ int   ri[4];
    __shared__ int   slots[33];
    int blk = blockIdx.x;
    int b = blk >> 5;              // 512 blocks: 16 batches x 32 groups
    int g = blk & 31;
    int t = threadIdx.x;
    const float* xb = xyz + (size_t)b * N_ * 3;
    for (int i = t; i < N_; i += 256)
        pts[i] = make_float4(xb[i*3+0], xb[i*3+1], xb[i*3+2], 0.f);
    __syncthreads();
    for (int mm = 0; mm < BQ_G; mm++) {
        int m = (g << 5) + mm;
        if (t == 0) cnt = 0;
        __syncthreads();   // barrier A: cnt reset visible; separates prev slots reads
        float4 c4 = pts[fps_idx[b*M_ + m]];
        float cx = c4.x, cy = c4.y, cz = c4.z;
        float bv = 3.4e38f; int bi = 0x7fffffff;
        for (int i = t; i < N_; i += 256) {
            float4 p = pts[i];
            float dx = p.x - cx, dy = p.y - cy, dz = p.z - cz;
            float t0 = dx*dx, t1 = dy*dy, t2 = dz*dz;
            float d = (t0 + t1) + t2;
            if (d < bv || (d == bv && i < bi)) { bv = d; bi = i; }
            if (d <= R2) {
                int pp = atomicAdd(&cnt, 1);
                if (pp < CAP) { cd[pp] = d; ci[pp] = i; }
            }
        }
        for (int off = 32; off >= 1; off >>= 1) {
            float ov = __shfl_xor(bv, off, 64);
            int   oi = __shfl_xor(bi, off, 64);
            if (ov < bv || (ov == bv && oi < bi)) { bv = ov; bi = oi; }
        }
        int w = t >> 6;
        if ((t & 63) == 0) { rv[w] = bv; ri[w] = bi; }
        __syncthreads();   // barrier B: cnt/cd/ci/rv/ri ready
        int n = cnt < CAP ? cnt : CAP;
        for (int j = t; j < n; j += 256) {
            float dj = cd[j]; int ij = ci[j];
            int rank = 0;
            for (int k = 0; k < n; k++) {
                float dk = cd[k]; int ik = ci[k];
                rank += (dk < dj) || (dk == dj && ik < ij);
            }
            if (rank < S_) slots[rank] = ij;
        }
        if (t == 0) {
            float v = rv[0]; int ix = ri[0];
            for (int j = 1; j < 4; j++)
                if (rv[j] < v || (rv[j] == v && ri[j] < ix)) { v = rv[j]; ix = ri[j]; }
            slots[32] = ix;
        }
        __syncthreads();   // barrier C: slots ready
        if (t < S_) {
            int nearest = (n > 0) ? slots[0] : slots[32];
            int ix = (t < n) ? slots[t] : nearest;
            ball_idx[(size_t)(b*M_ + m)*S_ + t] = ix;
        }
    }
}

// ============ Staged pipeline: each layer computed once ============
// zbuf: 2048 floats per center. S1 writes z0; S2 overwrites z1 in-place
// (each thread reads its own addresses to regs before writing them back).
// Weight rows are loaded in TWO register halves (wrh[32/36]) with an acc[]
// array -- same c-ascending accumulation order (bit-exact), ~45 fewer VGPRs
// -> higher occupancy for latency hiding.
// stats (NBUCK x 512): [sum0 64|sq0 64|sum1 64|sq1 64|sum2 128|sq2 128]

// S1: gather + L0 -> z0, stats0
__global__ __launch_bounds__(256) void mlpS1_kernel(
    const float* __restrict__ xyz, const float* __restrict__ feat,
    const int* __restrict__ fps_idx, const int* __restrict__ ball_idx,
    const float* __restrict__ w0, const float* __restrict__ b0,
    float* __restrict__ zbuf, float* __restrict__ stats) {
    __shared__ __align__(16) float xs[S_][68];   // col 67 = 0 pad
    __shared__ float red[256], red2[256];
    __shared__ int idxs[S_];
    int blk = blockIdx.x, b = blk >> 10, m = blk & (M_ - 1), t = threadIdx.x;
    const float* xb = xyz + (size_t)b * N_ * 3;
    int cidx = fps_idx[b*M_ + m];
    float cx = xb[cidx*3+0], cy = xb[cidx*3+1], cz = xb[cidx*3+2];
    if (t < S_) idxs[t] = ball_idx[(size_t)blk * S_ + t];
    __syncthreads();
    for (int i = t; i < S_*68; i += 256) {
        int s = i / 68, c = i - s * 68;
        int p = idxs[s];
        float v;
        if (c == 0)       v = xb[p*3+0] - cx;
        else if (c == 1)  v = xb[p*3+1] - cy;
        else if (c == 2)  v = xb[p*3+2] - cz;
        else if (c == 67) v = 0.f;
        else              v = feat[((size_t)b*N_ + p)*IN_ + (c - 3)];
        xs[s][c] = v;
    }
    __syncthreads();
    int d = t & 63;
    const float* w = w0 + d * C0IN;
    float bias = b0[d];
    float acc[8];
#pragma unroll
    for (int q = 0; q < 8; q++) acc[q] = bias;
    {   // half A: c = 0..31
        float wrh[32];
#pragma unroll
        for (int c = 0; c < 32; c++) wrh[c] = w[c];
#pragma unroll
        for (int q = 0; q < 8; q++) {
            int s = (t >> 6) + q * 4;
            const float4* x4 = (const float4*)&xs[s][0];
#pragma unroll
            for (int c4 = 0; c4 < 8; c4++) {
                float4 v = x4[c4];
                acc[q] += v.x * wrh[4*c4+0];
                acc[q] += v.y * wrh[4*c4+1];
                acc[q] += v.z * wrh[4*c4+2];
                acc[q] += v.w * wrh[4*c4+3];
            }
        }
    }
    {   // half B: c = 32..67 (35 real + 0 pad; xs[s][67] = 0)
        float wrh[36];
#pragma unroll
        for (int c = 0; c < 35; c++) wrh[c] = w[32 + c];
        wrh[35] = 0.f;
#pragma unroll
        for (int q = 0; q < 8; q++) {
            int s = (t >> 6) + q * 4;
            const float4* x4 = ((const float4*)&xs[s][0]) + 8;
#pragma unroll
            for (int c4 = 0; c4 < 9; c4++) {
                float4 v = x4[c4];
                acc[q] += v.x * wrh[4*c4+0];
                acc[q] += v.y * wrh[4*c4+1];
                acc[q] += v.z * wrh[4*c4+2];
                acc[q] += v.w * wrh[4*c4+3];
            }
        }
    }
    float lsum = 0.f, lsq = 0.f;
    float* zt = zbuf + (size_t)blk * 2048;
#pragma unroll
    for (int q = 0; q < 8; q++) {
        int s = (t >> 6) + q * 4;
        zt[s*64 + d] = acc[q];           // = zt[t + 256q], coalesced
        lsum += acc[q]; lsq += acc[q] * acc[q];
    }
    red[t] = lsum; red2[t] = lsq;
    __syncthreads();
    if (t < 64) {
        float* sb = stats + (size_t)(blk & (NBUCK-1)) * 512;
        atomicAdd(&sb[t],      red[t]  + red[t+64]  + red[t+128]  + red[t+192]);
        atomicAdd(&sb[64 + t], red2[t] + red2[t+64] + red2[t+128] + red2[t+192]);
    }
}

// S2: z0 -> BN0+relu -> L1 -> z1 (in-place), stats1
__global__ __launch_bounds__(256) void mlpS2_kernel(
    float* __restrict__ zbuf,
    const float* __restrict__ w1, const float* __restrict__ b1,
    const float* __restrict__ g0, const float* __restrict__ be0,
    float* __restrict__ stats) {
    __shared__ __align__(16) float y0s[S_][C0];
    __shared__ float red[256], red2[256];
    __shared__ float lc[128];
    int blk = blockIdx.x, t = threadIdx.x;
    const float inv_n = 1.0f / (float)NTOT;
    if (t < 64) {
        float s = 0.f, s2 = 0.f;
        for (int j = 0; j < NBUCK; j++) { s += stats[j*512 + t]; s2 += stats[j*512 + 64 + t]; }
        float mean = s * inv_n, var = s2 * inv_n - mean * mean;
        float a = g0[t] * (1.0f / sqrtf(var + 1e-5f));
        lc[t] = a; lc[64 + t] = be0[t] - mean * a;
    }
    int d = t & 63;
    float* zt = zbuf + (size_t)blk * 2048;
    float zv[8];
#pragma unroll
    for (int j = 0; j < 8; j++) zv[j] = zt[t + 256*j];   // channel d const across j
    const float* w = w1 + d * C0;
    float bias = b1[d];
    __syncthreads();   // lc ready
    float a0 = lc[d], c0 = lc[64 + d];
#pragma unroll
    for (int j = 0; j < 8; j++) {
        float v = zv[j] * a0 + c0;
        y0s[(t >> 6) + 4*j][d] = v > 0.f ? v : 0.f;
    }
    __syncthreads();   // y0s ready
    float acc[8];
#pragma unroll
    for (int q = 0; q < 8; q++) acc[q] = bias;
    {   // half A: c = 0..31
        float wrh[32];
#pragma unroll
        for (int c = 0; c < 32; c++) wrh[c] = w[c];
#pragma unroll
        for (int q = 0; q < 8; q++) {
            int s = (t >> 6) + q * 4;
            const float4* x4 = (const float4*)&y0s[s][0];
#pragma unroll
            for (int c4 = 0; c4 < 8; c4++) {
                float4 v = x4[c4];
                acc[q] += v.x * wrh[4*c4+0];
                acc[q] += v.y * wrh[4*c4+1];
                acc[q] += v.z * wrh[4*c4+2];
                acc[q] += v.w * wrh[4*c4+3];
            }
        }
    }
    {   // half B: c = 32..63
        float wrh[32];
#pragma unroll
        for (int c = 0; c < 32; c++) wrh[c] = w[32 + c];
#pragma unroll
        for (int q = 0; q < 8; q++) {
            int s = (t >> 6) + q * 4;
            const float4* x4 = ((const float4*)&y0s[s][0]) + 8;
#pragma unroll
            for (int c4 = 0; c4 < 8; c4++) {
                float4 v = x4[c4];
                acc[q] += v.x * wrh[4*c4+0];
                acc[q] += v.y * wrh[4*c4+1];
                acc[q] += v.z * wrh[4*c4+2];
                acc[q] += v.w * wrh[4*c4+3];
            }
        }
    }
    float lsum = 0.f, lsq = 0.f;
#pragma unroll
    for (int q = 0; q < 8; q++) {
        int s = (t >> 6) + q * 4;
        zt[s*64 + d] = acc[q];           // overwrite own read addresses (safe)
        lsum += acc[q]; lsq += acc[q] * acc[q];
    }
    red[t] = lsum; red2[t] = lsq;
    __syncthreads();
    if (t < 64) {
        float* sb = stats + (size_t)(blk & (NBUCK-1)) * 512;
        atomicAdd(&sb[128 + t], red[t]  + red[t+64]  + red[t+128]  + red[t+192]);
        atomicAdd(&sb[192 + t], red2[t] + red2[t+64] + red2[t+128] + red2[t+192]);
    }
}

// S3: z1 -> BN1+relu -> L2 -> stats2 (no store)
__global__ __launch_bounds__(256) void mlpS3_kernel(
    const float* __restrict__ zbuf,
    const float* __restrict__ w2, const float* __restrict__ b2,
    const float* __restrict__ g1, const float* __restrict__ be1,
    float* __restrict__ stats) {
    __shared__ __align__(16) float y1s[S_][C1];
    __shared__ float red[256], red2[256];
    __shared__ float lc[128];
    int blk = blockIdx.x, t = threadIdx.x;
    const float inv_n = 1.0f / (float)NTOT;
    if (t < 64) {
        float s = 0.f, s2 = 0.f;
        for (int j = 0; j < NBUCK; j++) { s += stats[j*512 + 128 + t]; s2 += stats[j*512 + 192 + t]; }
        float mean = s * inv_n, var = s2 * inv_n - mean * mean;
        float a = g1[t] * (1.0f / sqrtf(var + 1e-5f));
        lc[t] = a; lc[64 + t] = be1[t] - mean * a;
    }
    int dn = t & 63;
    const float* zt = zbuf + (size_t)blk * 2048;
    float zv[8];
#pragma unroll
    for (int j = 0; j < 8; j++) zv[j] = zt[t + 256*j];
    int d = t & 127;
    const float* w = w2 + d * C1;
    float bias = b2[d];
    __syncthreads();
    float a1 = lc[dn], c1 = lc[64 + dn];
#pragma unroll
    for (int j = 0; j < 8; j++) {
        float v = zv[j] * a1 + c1;
        y1s[(t >> 6) + 4*j][dn] = v > 0.f ? v : 0.f;
    }
    __syncthreads();
    float acc[16];
#pragma unroll
    for (int q = 0; q < 16; q++) acc[q] = bias;
    {   // half A
        float wrh[32];
#pragma unroll
        for (int c = 0; c < 32; c++) wrh[c] = w[c];
#pragma unroll
        for (int q = 0; q < 16; q++) {
            int s = (t >> 7) + q * 2;
            const float4* x4 = (const float4*)&y1s[s][0];
#pragma unroll
            for (int c4 = 0; c4 < 8; c4++) {
                float4 v = x4[c4];
                acc[q] += v.x * wrh[4*c4+0];
                acc[q] += v.y * wrh[4*c4+1];
                acc[q] += v.z * wrh[4*c4+2];
                acc[q] += v.w * wrh[4*c4+3];
            }
        }
    }
    {   // half B
        float wrh[32];
#pragma unroll
        for (int c = 0; c < 32; c++) wrh[c] = w[32 + c];
#pragma unroll
        for (int q = 0; q < 16; q++) {
            int s = (t >> 7) + q * 2;
            const float4* x4 = ((const float4*)&y1s[s][0]) + 8;
#pragma unroll
            for (int c4 = 0; c4 < 8; c4++) {
                float4 v = x4[c4];
                acc[q] += v.x * wrh[4*c4+0];
                acc[q] += v.y * wrh[4*c4+1];
                acc[q] += v.z * wrh[4*c4+2];
                acc[q] += v.w * wrh[4*c4+3];
            }
        }
    }
    float lsum = 0.f, lsq = 0.f;
#pragma unroll
    for (int q = 0; q < 16; q++) { lsum += acc[q]; lsq += acc[q] * acc[q]; }
    red[t] = lsum; red2[t] = lsq;
    __syncthreads();
    if (t < 128) {
        float* sb = stats + (size_t)(blk & (NBUCK-1)) * 512;
        atomicAdd(&sb[256 + t], red[t]  + red[t+128]);
        atomicAdd(&sb[384 + t], red2[t] + red2[t+128]);
    }
}

// S4: z1 -> BN1+relu -> L2 -> BN2+relu -> max -> out
__global__ __launch_bounds__(256) void mlpS4_kernel(
    const float* __restrict__ zbuf,
    const float* __restrict__ w2, const float* __restrict__ b2,
    const float* __restrict__ g1, const float* __restrict__ be1,
    const float* __restrict__ g2, const float* __restrict__ be2,
    const float* __restrict__ stats, float* __restrict__ out_feat) {
    __shared__ __align__(16) float y1s[S_][C1];
    __shared__ float red[256];
    __shared__ float lc[384];   // [a1 64|c1 64|a2 128|c2 128]
    int blk = blockIdx.x, t = threadIdx.x;
    const float inv_n = 1.0f / (float)NTOT;
    if (t < 64) {
        float s = 0.f, s2 = 0.f;
        for (int j = 0; j < NBUCK; j++) { s += stats[j*512 + 128 + t]; s2 += stats[j*512 + 192 + t]; }
        float mean = s * inv_n, var = s2 * inv_n - mean * mean;
        float a = g1[t] * (1.0f / sqrtf(var + 1e-5f));
        lc[t] = a; lc[64 + t] = be1[t] - mean * a;
    }
    if (t < 128) {
        float s = 0.f, s2 = 0.f;
        for (int j = 0; j < NBUCK; j++) { s += stats[j*512 + 256 + t]; s2 += stats[j*512 + 384 + t]; }
        float mean = s * inv_n, var = s2 * inv_n - mean * mean;
        float a = g2[t] * (1.0f / sqrtf(var + 1e-5f));
        lc[128 + t] = a; lc[256 + t] = be2[t] - mean * a;
    }
    int dn = t & 63;
    const float* zt = zbuf + (size_t)blk * 2048;
    float zv[8];
#pragma unroll
    for (int j = 0; j < 8; j++) zv[j] = zt[t + 256*j];
    int d = t & 127;
    const float* w = w2 + d * C1;
    float bias = b2[d];
    __syncthreads();
    float a1 = lc[dn], c1 = lc[64 + dn];
#pragma unroll
    for (int j = 0; j < 8; j++) {
        float v = zv[j] * a1 + c1;
        y1s[(t >> 6) + 4*j][dn] = v > 0.f ? v : 0.f;
    }
    __syncthreads();
    float acc[16];
#pragma unroll
    for (int q = 0; q < 16; q++) acc[q] = bias;
    {   // half A
        float wrh[32];
#pragma unroll
        for (int c = 0; c < 32; c++) wrh[c] = w[c];
#pragma unroll
        for (int q = 0; q < 16; q++) {
            int s = (t >> 7) + q * 2;
            const float4* x4 = (const float4*)&y1s[s][0];
#pragma unroll
            for (int c4 = 0; c4 < 8; c4++) {
                float4 v = x4[c4];
                acc[q] += v.x * wrh[4*c4+0];
                acc[q] += v.y * wrh[4*c4+1];
                acc[q] += v.z * wrh[4*c4+2];
                acc[q] += v.w * wrh[4*c4+3];
            }
        }
    }
    {   // half B
        float wrh[32];
#pragma unroll
        for (int c = 0; c < 32; c++) wrh[c] = w[32 + c];
#pragma unroll
        for (int q = 0; q < 16; q++) {
            int s = (t >> 7) + q * 2;
            const float4* x4 = ((const float4*)&y1s[s][0]) + 8;
#pragma unroll
            for (int c4 = 0; c4 < 8; c4++) {
                float4 v = x4[c4];
                acc[q] += v.x * wrh[4*c4+0];
                acc[q] += v.y * wrh[4*c4+1];
                acc[q] += v.z * wrh[4*c4+2];
                acc[q] += v.w * wrh[4*c4+3];
            }
        }
    }
    float a2 = lc[128 + d], c2 = lc[256 + d];
    float lmax = -3.4e38f;
#pragma unroll
    for (int q = 0; q < 16; q++) {
        float v = acc[q] * a2 + c2;
        v = v > 0.f ? v : 0.f;
        lmax = v > lmax ? v : lmax;
    }
    red[t] = lmax;
    __syncthreads();
    if (t < 128) {
        float v = red[t] > red[t+128] ? red[t] : red[t+128];
        out_feat[(size_t)blk * C2 + t] = v;
    }
}

// uniform-broadcast float4 dot for the fallback path
template<int STEPS>
__device__ __forceinline__ float dot4u(const float4* __restrict__ x4,
                                       const float (&wr)[STEPS*4], float acc) {
#pragma unroll
    for (int c4 = 0; c4 < STEPS; c4++) {
        float4 v = x4[c4];
        acc += v.x * wr[4*c4+0];
        acc += v.y * wr[4*c4+1];
        acc += v.z * wr[4*c4+2];
        acc += v.w * wr[4*c4+3];
    }
    return acc;
}

// ============ Fallback 4-pass MLP (exact round-5, proven; ws-too-small path) ============
template<int MODE>
__global__ __launch_bounds__(256) void mlp_kernel(
    const float* __restrict__ xyz, const float* __restrict__ feat,
    const int* __restrict__ fps_idx, const int* __restrict__ ball_idx,
    const float* __restrict__ w0, const float* __restrict__ b0,
    const float* __restrict__ g0, const float* __restrict__ be0,
    const float* __restrict__ w1, const float* __restrict__ b1,
    const float* __restrict__ g1, const float* __restrict__ be1,
    const float* __restrict__ w2, const float* __restrict__ b2,
    const float* __restrict__ g2, const float* __restrict__ be2,
    float* __restrict__ stats, float* __restrict__ out_feat) {
    __shared__ __align__(16) float xs[S_][68];
    __shared__ __align__(16) float y0s[S_][C0];
    __shared__ __align__(16) float y1s[S_][C1];
    __shared__ float red[256], red2[256];
    __shared__ float lc[512];
    __shared__ int idxs[S_];
    int blk = blockIdx.x;
    int b = blk >> 10, m = blk & (M_ - 1);
    int t = threadIdx.x;
    const float inv_n = 1.0f / (float)NTOT;
    if (MODE >= 1 && t < 64) {
        float s = 0.f, s2 = 0.f;
        for (int j = 0; j < NBUCK; j++) { s += stats[j*512 + t]; s2 += stats[j*512 + 64 + t]; }
        float mean = s * inv_n, var = s2 * inv_n - mean * mean;
        float a = g0[t] * (1.0f / sqrtf(var + 1e-5f));
        lc[t] = a; lc[64 + t] = be0[t] - mean * a;
    }
    if (MODE >= 2 && t < 64) {
        float s = 0.f, s2 = 0.f;
        for (int j = 0; j < NBUCK; j++) { s += stats[j*512 + 128 + t]; s2 += stats[j*512 + 192 + t]; }
        float mean = s * inv_n, var = s2 * inv_n - mean * mean;
        float a = g1[t] * (1.0f / sqrtf(var + 1e-5f));
        lc[128 + t] = a; lc[192 + t] = be1[t] - mean * a;
    }
    if (MODE == 3 && t < 128) {
        float s = 0.f, s2 = 0.f;
        for (int j = 0; j < NBUCK; j++) { s += stats[j*512 + 256 + t]; s2 += stats[j*512 + 384 + t]; }
        float mean = s * inv_n, var = s2 * inv_n - mean * mean;
        float a = g2[t] * (1.0f / sqrtf(var + 1e-5f));
        lc[256 + t] = a; lc[384 + t] = be2[t] - mean * a;
    }
    const float* xb = xyz + (size_t)b * N_ * 3;
    int cidx = fps_idx[b*M_ + m];
    float cx = xb[cidx*3+0], cy = xb[cidx*3+1], cz = xb[cidx*3+2];
    if (t < S_) idxs[t] = ball_idx[(size_t)blk * S_ + t];
    __syncthreads();
    for (int i = t; i < S_*68; i += 256) {
        int s = i / 68, c = i - s * 68;
        int p = idxs[s];
        float v;
        if (c == 0)       v = xb[p*3+0] - cx;
        else if (c == 1)  v = xb[p*3+1] - cy;
        else if (c == 2)  v = xb[p*3+2] - cz;
        else if (c == 67) v = 0.f;
        else              v = feat[((size_t)b*N_ + p)*IN_ + (c - 3)];
        xs[s][c] = v;
    }
    __syncthreads();
    {
        int d = t & 63;
        float wr[68];
        {
            const float* w = w0 + d * C0IN;
#pragma unroll
            for (int c = 0; c < C0IN; c++) wr[c] = w[c];
            wr[67] = 0.f;
        }
        float bias = b0[d];
        float lsum = 0.f, lsq = 0.f;
#pragma unroll
        for (int q = 0; q < 8; q++) {
            int s = (t >> 6) + q * 4;
            float acc = dot4u<17>((const float4*)&xs[s][0], wr, bias);
            if (MODE == 0) { lsum += acc; lsq += acc * acc; }
            else {
                float v = acc * lc[d] + lc[64 + d];
                y0s[s][d] = v > 0.f ? v : 0.f;
            }
        }
        if (MODE == 0) {
            red[t] = lsum; red2[t] = lsq;
            __syncthreads();
            if (t < 64) {
                float* sb = stats + (size_t)(blk & (NBUCK-1)) * 512;
                atomicAdd(&sb[t],      red[t]  + red[t+64]  + red[t+128]  + red[t+192]);
                atomicAdd(&sb[64 + t], red2[t] + red2[t+64] + red2[t+128] + red2[t+192]);
            }
            return;
        }
    }
    __syncthreads();
    {
        int d = t & 63;
        float wr[64];
        {
            const float* w = w1 + d * C0;
#pragma unroll
            for (int c = 0; c < C0; c++) wr[c] = w[c];
        }
        float bias = b1[d];
        float lsum = 0.f, lsq = 0.f;
#pragma unroll
        for (int q = 0; q < 8; q++) {
            int s = (t >> 6) + q * 4;
            float acc = dot4u<16>((const float4*)&y0s[s][0], wr, bias);
            if (MODE == 1) { lsum += acc; lsq += acc * acc; }
            else {
                float v = acc * lc[128 + d] + lc[192 + d];
                y1s[s][d] = v > 0.f ? v : 0.f;
            }
        }
        if (MODE == 1) {
            red[t] = lsum; red2[t] = lsq;
            __syncthreads();
            if (t < 64) {
                float* sb = stats + (size_t)(blk & (NBUCK-1)) * 512;
                atomicAdd(&sb[128 + t], red[t]  + red[t+64]  + red[t+128]  + red[t+192]);
                atomicAdd(&sb[192 + t], red2[t] + red2[t+64] + red2[t+128] + red2[t+192]);
            }
            return;
        }
    }
    __syncthreads();
    {
        int d = t & 127;
        float wr[64];
        {
            const float* w = w2 + d * C1;
#pragma unroll
            for (int c = 0; c < C1; c++) wr[c] = w[c];
        }
        float bias = b2[d];
        float lsum = 0.f, lsq = 0.f, lmax = -3.4e38f;
#pragma unroll
        for (int q = 0; q < 16; q++) {
            int s = (t >> 7) + q * 2;
            float acc = dot4u<16>((const float4*)&y1s[s][0], wr, bias);
            if (MODE == 2) { lsum += acc; lsq += acc * acc; }
            else {
                float v = acc * lc[256 + d] + lc[384 + d];
                v = v > 0.f ? v : 0.f;
                lmax = v > lmax ? v : lmax;
            }
        }
        if (MODE == 2) {
            red[t] = lsum; red2[t] = lsq;
            __syncthreads();
            if (t < 128) {
                float* sb = stats + (size_t)(blk & (NBUCK-1)) * 512;
                atomicAdd(&sb[256 + t], red[t]  + red[t+128]);
                atomicAdd(&sb[384 + t], red2[t] + red2[t+128]);
            }
            return;
        }
        red[t] = lmax;
        __syncthreads();
        if (t < 128) {
            float v = red[t] > red[t+128] ? red[t] : red[t+128];
            out_feat[(size_t)blk * C2 + t] = v;
        }
    }
}

extern "C" void kernel_launch(void* const* d_in, const int* in_sizes, int n_in,
                              void* d_out, int out_size, void* d_ws, size_t ws_size,
                              hipStream_t stream) {
    const float* xyz  = (const float*)d_in[0];
    const float* feat = (const float*)d_in[1];
    const float* w0 = (const float*)d_in[2];  const float* b0 = (const float*)d_in[3];
    const float* g0 = (const float*)d_in[4];  const float* be0 = (const float*)d_in[5];
    const float* w1 = (const float*)d_in[6];  const float* b1 = (const float*)d_in[7];
    const float* g1 = (const float*)d_in[8];  const float* be1 = (const float*)d_in[9];
    const float* w2 = (const float*)d_in[10]; const float* b2 = (const float*)d_in[11];
    const float* g2 = (const float*)d_in[12]; const float* be2 = (const float*)d_in[13];
    float* out_xyz  = (float*)d_out;
    float* out_feat = out_xyz + B_*M_*3;

    int* fps_i  = (int*)d_ws;                                   // 64 KB
    int* ball_i = (int*)((char*)d_ws + 65536);                  // 2 MB
    float* stats = (float*)((char*)d_ws + 65536 + 2097152);     // NBUCK*512*4 = 32 KB
    size_t zoff = 65536 + 2097152 + (size_t)NBUCK*512*4;        // aligned
    float* zbuf = (float*)((char*)d_ws + zoff);                 // 16384*2048*4 = 128 MB
    size_t need = zoff + (size_t)B_*M_ * 2048 * 4;
    bool staged = ws_size >= need;

    hipMemsetAsync(stats, 0, NBUCK*512*sizeof(float), stream);
    fps_kernel<<<B_, FPS_T, 0, stream>>>(xyz, fps_i, out_xyz);
    ballq_kernel<<<B_ * (M_/BQ_G), 256, 0, stream>>>(xyz, fps_i, ball_i);

    if (staged) {
        mlpS1_kernel<<<B_*M_, 256, 0, stream>>>(xyz, feat, fps_i, ball_i, w0, b0, zbuf, stats);
        mlpS2_kernel<<<B_*M_, 256, 0, stream>>>(zbuf, w1, b1, g0, be0, stats);
        mlpS3_kernel<<<B_*M_, 256, 0, stream>>>(zbuf, w2, b2, g1, be1, stats);
        mlpS4_kernel<<<B_*M_, 256, 0, stream>>>(zbuf, w2, b2, g1, be1, g2, be2, stats, out_feat);
    } else {
        mlp_kernel<0><<<B_*M_, 256, 0, stream>>>(xyz, feat, fps_i, ball_i,
            w0, b0, g0, be0, w1, b1, g1, be1, w2, b2, g2, be2, stats, out_feat);
        mlp_kernel<1><<<B_*M_, 256, 0, stream>>>(xyz, feat, fps_i, ball_i,
            w0, b0, g0, be0, w1, b1, g1, be1, w2, b2, g2, be2, stats, out_feat);
        mlp_kernel<2><<<B_*M_, 256, 0, stream>>>(xyz, feat, fps_i, ball_i,
            w0, b0, g0, be0, w1, b1, g1, be1, w2, b2, g2, be2, stats, out_feat);
        mlp_kernel<3><<<B_*M_, 256, 0, stream>>>(xyz, feat, fps_i, ball_i,
            w0, b0, g0, be0, w1, b1, g1, be1, w2, b2, g2, be2, stats, out_feat);
    }
}